// Round 11
// baseline (991.240 us; speedup 1.0000x reference)
//
#include <hip/hip_runtime.h>

typedef unsigned int uint;
typedef unsigned short u16;

#define BB 4
#define CE 384
#define DD 512
#define LL 8
#define HH 16
#define MM 2048
#define NJ 163
#define TOK 4096
#define BKQ 64
#define QH 256
#define OUTW 1486
#define NROT 978
#define QKSCALE 0.17677669529663687f

typedef __attribute__((ext_vector_type(8))) short short8;
typedef __attribute__((ext_vector_type(4))) float float4v;

static __device__ __forceinline__ u16 f2bf(float f){
  union { float f; uint u; } c; c.f = f;
  uint u = c.u;
  return (u16)((u + 0x7FFFu + ((u >> 16) & 1u)) >> 16);
}
static __device__ __forceinline__ float bf2f(u16 u){
  union { uint u; float f; } c; c.u = ((uint)u) << 16;
  return c.f;
}
static __device__ __forceinline__ float wred_sum(float v){
  for (int o = 32; o; o >>= 1) v += __shfl_xor(v, o, 64);
  return v;
}
static __device__ __forceinline__ void gl16(const void* g, void* l){
  __builtin_amdgcn_global_load_lds((const __attribute__((address_space(1))) void*)g,
                                   (__attribute__((address_space(3))) void*)l, 16, 0, 0);
}

// ---------------- AT tile: AT[(h*512+dout)][din] = QKSCALE*sum_dh Wq[din][h*32+dh]*Wk[dout][h*32+dh] ----------------
static __device__ void d_wqk(const float* __restrict__ wq, const float* __restrict__ wk,
    u16* __restrict__ AT, int id, int t, u16* As, u16* Bs)
{
  int rt = id & 127, dt = id >> 7;
  int h = rt >> 3, dout0 = (rt & 7)*64, din0 = dt*64;
  int r = t >> 2, c0 = (t & 3)*8;
  {
    float4 u0 = *(const float4*)(wk + (size_t)(dout0+r)*DD + h*32 + c0);
    float4 u1 = *(const float4*)(wk + (size_t)(dout0+r)*DD + h*32 + c0 + 4);
    u16* d = As + r*40 + c0;
    d[0]=f2bf(u0.x); d[1]=f2bf(u0.y); d[2]=f2bf(u0.z); d[3]=f2bf(u0.w);
    d[4]=f2bf(u1.x); d[5]=f2bf(u1.y); d[6]=f2bf(u1.z); d[7]=f2bf(u1.w);
    float4 v0 = *(const float4*)(wq + (size_t)(din0+r)*DD + h*32 + c0);
    float4 v1 = *(const float4*)(wq + (size_t)(din0+r)*DD + h*32 + c0 + 4);
    u16* e = Bs + r*40 + c0;
    e[0]=f2bf(v0.x); e[1]=f2bf(v0.y); e[2]=f2bf(v0.z); e[3]=f2bf(v0.w);
    e[4]=f2bf(v1.x); e[5]=f2bf(v1.y); e[6]=f2bf(v1.z); e[7]=f2bf(v1.w);
  }
  __syncthreads();
  int lane = t & 63, w = t >> 6, lr = lane & 15, lk = lane >> 4;
  short8 af = *(const short8*)&As[(w*16+lr)*40 + lk*8];
  float4v acc[4];
  float4v z4 = {0.f,0.f,0.f,0.f};
  acc[0]=z4; acc[1]=z4; acc[2]=z4; acc[3]=z4;
  #pragma unroll
  for (int nf = 0; nf < 4; nf++){
    short8 bf8 = *(const short8*)&Bs[(nf*16+lr)*40 + lk*8];
    acc[nf] = __builtin_amdgcn_mfma_f32_16x16x32_bf16(af, bf8, acc[nf], 0, 0, 0);
  }
  #pragma unroll
  for (int nf = 0; nf < 4; nf++){
    #pragma unroll
    for (int jj = 0; jj < 4; jj++){
      int row = w*16 + lk*4 + jj;
      AT[(size_t)(h*512 + dout0 + row)*DD + din0 + nf*16 + lr] = f2bf(acc[nf][jj]*QKSCALE);
    }
  }
}

// ---------------- WVO tile: WVOT[dout][(h*512+Dc)] = sum_c Wv[Dc][h*32+c]*Wo[h*32+c][dout] ----------------
static __device__ void d_wvo(const float* __restrict__ wv, const float* __restrict__ wo,
    u16* __restrict__ WVOT, int id, int t, u16* As, u16* Bs)
{
  int ct = id & 127, dt = id >> 7;
  int h = ct >> 3, Dc0 = (ct & 7)*64, dout0 = dt*64;
  {
    int c = t >> 3, d8 = (t & 7)*8;
    float4 a0 = *(const float4*)(wo + (size_t)(h*32+c)*DD + dout0 + d8);
    float4 a1 = *(const float4*)(wo + (size_t)(h*32+c)*DD + dout0 + d8 + 4);
    As[(d8+0)*40 + c] = f2bf(a0.x);
    As[(d8+1)*40 + c] = f2bf(a0.y);
    As[(d8+2)*40 + c] = f2bf(a0.z);
    As[(d8+3)*40 + c] = f2bf(a0.w);
    As[(d8+4)*40 + c] = f2bf(a1.x);
    As[(d8+5)*40 + c] = f2bf(a1.y);
    As[(d8+6)*40 + c] = f2bf(a1.z);
    As[(d8+7)*40 + c] = f2bf(a1.w);
    int r = t >> 2, c0 = (t & 3)*8;
    float4 v0 = *(const float4*)(wv + (size_t)(Dc0+r)*DD + h*32 + c0);
    float4 v1 = *(const float4*)(wv + (size_t)(Dc0+r)*DD + h*32 + c0 + 4);
    u16* e = Bs + r*40 + c0;
    e[0]=f2bf(v0.x); e[1]=f2bf(v0.y); e[2]=f2bf(v0.z); e[3]=f2bf(v0.w);
    e[4]=f2bf(v1.x); e[5]=f2bf(v1.y); e[6]=f2bf(v1.z); e[7]=f2bf(v1.w);
  }
  __syncthreads();
  int lane = t & 63, w = t >> 6, lr = lane & 15, lk = lane >> 4;
  short8 af = *(const short8*)&As[(w*16+lr)*40 + lk*8];
  float4v acc[4];
  float4v z4 = {0.f,0.f,0.f,0.f};
  acc[0]=z4; acc[1]=z4; acc[2]=z4; acc[3]=z4;
  #pragma unroll
  for (int nf = 0; nf < 4; nf++){
    short8 bf8 = *(const short8*)&Bs[(nf*16+lr)*40 + lk*8];
    acc[nf] = __builtin_amdgcn_mfma_f32_16x16x32_bf16(af, bf8, acc[nf], 0, 0, 0);
  }
  #pragma unroll
  for (int nf = 0; nf < 4; nf++){
    #pragma unroll
    for (int jj = 0; jj < 4; jj++){
      int row = w*16 + lk*4 + jj;
      WVOT[(size_t)(dout0 + row)*8192 + h*512 + Dc0 + nf*16 + lr] = f2bf(acc[nf][jj]);
    }
  }
}

// ---------------- unified prep: NMS + transposes + pose-const + bias + layer-0 AT/WVO ----------------
struct PJobs {
  const float* s[24]; u16* d[24];
  int R[24], C[24], t0[25];
  int njobs, ntiles;
};
__global__ __launch_bounds__(256) void k_prep_all(PJobs J,
    const float* __restrict__ scores,
    int* __restrict__ oidx, float* __restrict__ omask, float* __restrict__ ocol, float* __restrict__ orow,
    const float* __restrict__ pW1, const float* __restrict__ pb1,
    const float* __restrict__ ibp, float* __restrict__ hb4,
    const float* __restrict__ offb1, const float* __restrict__ db1, const float* __restrict__ sb1,
    const float* __restrict__ pb2, float* __restrict__ cvec2,
    const float* __restrict__ Wq, const float* __restrict__ Wk,
    const float* __restrict__ Wv, const float* __restrict__ Wo,
    u16* __restrict__ AT0, u16* __restrict__ WVO0)
{
  int bid = blockIdx.x, t = threadIdx.x;
  __shared__ float sraw[4096];
  __shared__ float sv[4]; __shared__ int si[4]; __shared__ int swin;
  __shared__ u16 tb[32][66];
  __shared__ __align__(16) u16 Aw[2560];
  __shared__ __align__(16) u16 Bw[2560];

  if (bid < 4){
    int b = bid;
    const float* sp = scores + (size_t)b * 4096;
    for (int i = t; i < 4096; i += 256) sraw[i] = sp[i];
    __syncthreads();
    float v[16];
    #pragma unroll
    for (int j = 0; j < 16; j++){
      int i = t + j*256;
      int r = i >> 6, c = i & 63;
      float mx = -1e30f;
      for (int dr = -1; dr <= 1; dr++){
        int rr = r + dr; if (rr < 0 || rr > 63) continue;
        for (int dc = -1; dc <= 1; dc++){
          int cc = c + dc; if (cc < 0 || cc > 63) continue;
          mx = fmaxf(mx, sraw[rr*64+cc]);
        }
      }
      float s = sraw[i];
      v[j] = (s == mx) ? s : 0.0f;
    }
    int lane = t & 63, wv = t >> 6;
    for (int iter = 0; iter < 16; iter++){
      float best = -1e30f; int bi_ = 1 << 30;
      #pragma unroll
      for (int j = 0; j < 16; j++){
        if (v[j] > best){ best = v[j]; bi_ = t + j*256; }
      }
      #pragma unroll
      for (int o = 32; o; o >>= 1){
        float ov = __shfl_xor(best, o, 64);
        int oi = __shfl_xor(bi_, o, 64);
        if (ov > best || (ov == best && oi < bi_)){ best = ov; bi_ = oi; }
      }
      if (lane == 0){ sv[wv] = best; si[wv] = bi_; }
      __syncthreads();
      if (t == 0){
        float bb = sv[0]; int ii = si[0];
        for (int k = 1; k < 4; k++){
          if (sv[k] > bb || (sv[k] == bb && si[k] < ii)){ bb = sv[k]; ii = si[k]; }
        }
        oidx[b*16+iter] = ii;
        omask[b*16+iter] = (bb >= 0.3f) ? 1.f : 0.f;
        ocol[b*16+iter] = (float)(ii & 63);
        orow[b*16+iter] = (float)(ii >> 6);
        swin = ii;
      }
      __syncthreads();
      int wi = swin;
      if ((wi & 255) == t) v[wi >> 8] = -1e30f;
      __syncthreads();
    }
  } else if (bid < 132){
    int d = (bid - 4)*4 + (t >> 6);
    int ln = t & 63;
    float acc = 0.f;
    for (int i = ln; i < NJ*6; i += 64) acc += ibp[i] * pW1[(size_t)(DD+i)*DD + d];
    acc = wred_sum(acc);
    if (ln == 0) hb4[1536 + d] = acc + pb1[d];
  } else if (bid == 132){
    for (int i = t; i < 1536; i += 256)
      hb4[i] = (i < 512) ? offb1[i] : (i < 1024 ? db1[i-512] : sb1[i-1024]);
    for (int i = t; i < 1024; i += 256)
      cvec2[i] = (i < NJ*6) ? (pb2[i] + ibp[i]) : 0.f;
  }

  // ---- transpose tiles: 64(r) x 32(c), bf16 LDS, packed-uint coalesced writes ----
  for (int g = bid; g < J.ntiles; g += gridDim.x){
    int j = 0;
    while (g >= J.t0[j+1]) j++;
    int ti = g - J.t0[j];
    int C_ = J.C[j], R_ = J.R[j];
    int tC = (C_ + 31) >> 5;
    int ry = ti / tC, cx = ti - ry*tC;
    int r0 = ry*64, c0 = cx*32;
    int tx = t & 31, ty = t >> 5;
    const float* src = J.s[j]; u16* dst = J.d[j];
    __syncthreads();
    #pragma unroll
    for (int i = 0; i < 8; i++){
      int r = ty + i*8;
      float v = 0.f;
      if (c0+tx < C_) v = src[(size_t)(r0+r)*C_ + c0+tx];
      tb[tx][r] = f2bf(v);
    }
    __syncthreads();
    #pragma unroll
    for (int p = 0; p < 4; p++){
      int c = (t >> 5) + p*8;
      int rr = t & 31;
      if (c0 + c < C_){
        uint val = (uint)tb[c][2*rr] | ((uint)tb[c][2*rr+1] << 16);
        *(uint*)&dst[(size_t)(c0+c)*R_ + r0 + rr*2] = val;
      }
    }
  }

  // ---- layer-0 AT/WVO fold (grid is exactly 2048 = tile count) ----
  __syncthreads();
  if (bid < 1024) d_wqk(Wq, Wk, AT0, bid, t, Aw, Bw);
  else d_wvo(Wv, Wo, WVO0, bid - 1024, t, Aw, Bw);
}

// ---------------- ctx embed GEMM: ctx = feat(fp32) @ wtokT^T + btok + pos_emb -> bf16 ctx + ctxT ----------------
__global__ __launch_bounds__(256) void k_gemm_emb(
    const float* __restrict__ feat, const u16* __restrict__ Bt,
    u16* __restrict__ ctx, u16* __restrict__ ctxT,
    const float* __restrict__ ep1, const float* __restrict__ ep2)
{
  __shared__ __align__(16) u16 SM[16640];
  u16* As = SM;
  u16* Bs = SM + 8192;
  int m0 = blockIdx.y*128, n0 = blockIdx.x*128;
  int t = threadIdx.x, lane = t & 63, wave = t >> 6;
  int wr = wave >> 1, wc = wave & 1;
  int lr = lane & 15, lk = lane >> 4;
  int sr8 = t >> 3, sl = t & 7;
  int sw = ((sl ^ (sr8 & 7)) * 8);
  float4v acc[4][4];
  float4v z4 = {0.f, 0.f, 0.f, 0.f};
  #pragma unroll
  for (int i = 0; i < 4; i++)
    #pragma unroll
    for (int j = 0; j < 4; j++) acc[i][j] = z4;
  for (int kt = 0; kt < CE; kt += 64){
    __syncthreads();
    #pragma unroll
    for (int p = 0; p < 8; p++){
      int r = (t >> 4) + p*16, f4 = t & 15;
      float4 v = *(const float4*)&feat[(size_t)(m0+r)*CE + kt + f4*4];
      int dc = ((f4 >> 1) ^ (r & 7))*8 + (f4 & 1)*4;
      ushort4 o; o.x = f2bf(v.x); o.y = f2bf(v.y); o.z = f2bf(v.z); o.w = f2bf(v.w);
      *(ushort4*)&As[r*64 + dc] = o;
    }
    #pragma unroll
    for (int rg = 0; rg < 4; rg++)
      gl16(Bt + (size_t)(n0 + rg*32 + sr8)*CE + kt + sw, Bs + rg*2048 + 8*t);
    __syncthreads();
    #pragma unroll
    for (int s = 0; s < 2; s++){
      int slot = ((s*4 + lk) ^ (lr & 7)) * 8;
      short8 af[4], bfr[4];
      #pragma unroll
      for (int i = 0; i < 4; i++) af[i] = *(const short8*)&As[(wr*64 + i*16 + lr)*64 + slot];
      #pragma unroll
      for (int j = 0; j < 4; j++) bfr[j] = *(const short8*)&Bs[(wc*64 + j*16 + lr)*64 + slot];
      #pragma unroll
      for (int i = 0; i < 4; i++)
        #pragma unroll
        for (int j = 0; j < 4; j++)
          acc[i][j] = __builtin_amdgcn_mfma_f32_16x16x32_bf16(af[i], bfr[j], acc[i][j], 0, 0, 0);
    }
  }
  __syncthreads();
  #pragma unroll
  for (int i = 0; i < 4; i++){
    int rbase = m0 + wr*64 + i*16 + lk*4;
    #pragma unroll
    for (int j = 0; j < 4; j++){
      int cc = n0 + wc*64 + j*16 + lr;
      #pragma unroll
      for (int jj = 0; jj < 4; jj++){
        int rr = rbase + jj;
        float vv = acc[i][j][jj] + ep1[cc] + ep2[(size_t)(rr & 4095)*DD + cc];
        u16 bv = f2bf(vv);
        ctx[(size_t)rr*DD + cc] = bv;
        SM[(cc - n0)*130 + (rr - m0)] = bv;
      }
    }
  }
  __syncthreads();
  int b = m0 >> 12, tok0 = m0 & 4095;
  int tx = t & 63, ty = t >> 6;
  #pragma unroll 4
  for (int it = 0; it < 32; it++){
    int c = ty*32 + it;
    uint vv = *(const uint*)&SM[c*130 + tx*2];
    *(uint*)&ctxT[((size_t)b*DD + n0 + c)*TOK + tok0 + tx*2] = vv;
  }
}

// ---------------- gather x0 from ctx rows (bf16 -> fp32) ----------------
__global__ __launch_bounds__(256) void k_gather2(const u16* __restrict__ ctx, const int* __restrict__ oidx,
    float* __restrict__ x)
{
  int bq = blockIdx.x, t = threadIdx.x;
  int b = bq >> 4, tok = oidx[bq];
  uint v = ((const uint*)(ctx + ((size_t)b*TOK + tok)*DD))[t];
  float2 o; o.x = bf2f((u16)(v & 0xFFFF)); o.y = bf2f((u16)(v >> 16));
  *(float2*)&x[(size_t)bq*DD + t*2] = o;
}

// ---------------- logits GEMM: 128x64 tiles, bf16 out ----------------
__global__ __launch_bounds__(256) void k_gemm_logits(
    const u16* __restrict__ A, const u16* __restrict__ Bt, u16* __restrict__ Cb)
{
  int bz = blockIdx.z;
  const u16* Ab = A + (size_t)bz*QH*DD;
  const u16* Bb = Bt + (size_t)bz*TOK*DD;
  int m0 = blockIdx.y*128, n0 = blockIdx.x*64;
  __shared__ __align__(16) u16 As[128*64];
  __shared__ __align__(16) u16 Bs[64*64];
  int t = threadIdx.x, lane = t & 63, w = t >> 6;
  int lr = lane & 15, lk = lane >> 4;
  int sr8 = t >> 3, sl = t & 7;
  int sw = ((sl ^ (sr8 & 7)) * 8);
  float4v acc[2][4];
  float4v z4 = {0.f,0.f,0.f,0.f};
  #pragma unroll
  for (int i = 0; i < 2; i++)
    #pragma unroll
    for (int j = 0; j < 4; j++) acc[i][j] = z4;
  for (int kt = 0; kt < DD; kt += 64){
    __syncthreads();
    #pragma unroll
    for (int rg = 0; rg < 4; rg++)
      gl16(Ab + (size_t)(m0 + rg*32 + sr8)*DD + kt + sw, As + rg*2048 + 8*t);
    #pragma unroll
    for (int rg = 0; rg < 2; rg++)
      gl16(Bb + (size_t)(n0 + rg*32 + sr8)*DD + kt + sw, Bs + rg*2048 + 8*t);
    __syncthreads();
    #pragma unroll
    for (int s = 0; s < 2; s++){
      int slot = ((s*4 + lk) ^ (lr & 7)) * 8;
      short8 af[2], bfr[4];
      #pragma unroll
      for (int i = 0; i < 2; i++) af[i] = *(const short8*)&As[(w*32 + i*16 + lr)*64 + slot];
      #pragma unroll
      for (int j = 0; j < 4; j++) bfr[j] = *(const short8*)&Bs[(j*16 + lr)*64 + slot];
      #pragma unroll
      for (int i = 0; i < 2; i++)
        #pragma unroll
        for (int j = 0; j < 4; j++)
          acc[i][j] = __builtin_amdgcn_mfma_f32_16x16x32_bf16(af[i], bfr[j], acc[i][j], 0, 0, 0);
    }
  }
  #pragma unroll
  for (int i = 0; i < 2; i++){
    int rbase = m0 + w*32 + i*16 + lk*4;
    #pragma unroll
    for (int j = 0; j < 4; j++){
      int cc = n0 + j*16 + lr;
      #pragma unroll
      for (int jj = 0; jj < 4; jj++){
        int rr = rbase + jj;
        Cb[(size_t)bz*QH*TOK + (size_t)rr*TOK + cc] = f2bf(acc[i][j][jj]);
      }
    }
  }
}

// ---------------- PV GEMM (128x64, bf16 split-K partials) + next-layer AT/WVO fold ----------------
__global__ __launch_bounds__(256) void k_pv_fused(
    const u16* __restrict__ att, const u16* __restrict__ ctxT, u16* __restrict__ parts,
    const float* __restrict__ wq, const float* __restrict__ wk,
    const float* __restrict__ wv, const float* __restrict__ wo,
    u16* __restrict__ AT, u16* __restrict__ WVO)
{
  __shared__ __align__(16) u16 As[128*64];
  __shared__ __align__(16) u16 Bs[64*64];
  int bz = blockIdx.z, t = threadIdx.x;
  if (bz >= 32){
    int id = (bz - 32)*16 + blockIdx.y*8 + blockIdx.x;
    if (id < 1024) d_wqk(wq, wk, AT, id, t, As, As + 2560);
    else d_wvo(wv, wo, WVO, id - 1024, t, As, As + 2560);
    return;
  }
  int batch = bz >> 3, ks = bz & 7;
  const u16* Ab = att + (size_t)batch*QH*TOK + (size_t)ks*512;
  const u16* Bb = ctxT + (size_t)batch*DD*TOK + (size_t)ks*512;
  int m0 = blockIdx.y*128, n0 = blockIdx.x*64;
  int lane = t & 63, w = t >> 6;
  int lr = lane & 15, lk = lane >> 4;
  int sr8 = t >> 3, sl = t & 7;
  int sw = ((sl ^ (sr8 & 7)) * 8);
  float4v acc[2][4];
  float4v z4 = {0.f,0.f,0.f,0.f};
  #pragma unroll
  for (int i = 0; i < 2; i++)
    #pragma unroll
    for (int j = 0; j < 4; j++) acc[i][j] = z4;
  for (int kt = 0; kt < 512; kt += 64){
    __syncthreads();
    #pragma unroll
    for (int rg = 0; rg < 4; rg++)
      gl16(Ab + (size_t)(m0 + rg*32 + sr8)*TOK + kt + sw, As + rg*2048 + 8*t);
    #pragma unroll
    for (int rg = 0; rg < 2; rg++)
      gl16(Bb + (size_t)(n0 + rg*32 + sr8)*TOK + kt + sw, Bs + rg*2048 + 8*t);
    __syncthreads();
    #pragma unroll
    for (int s = 0; s < 2; s++){
      int slot = ((s*4 + lk) ^ (lr & 7)) * 8;
      short8 af[2], bfr[4];
      #pragma unroll
      for (int i = 0; i < 2; i++) af[i] = *(const short8*)&As[(w*32 + i*16 + lr)*64 + slot];
      #pragma unroll
      for (int j = 0; j < 4; j++) bfr[j] = *(const short8*)&Bs[(j*16 + lr)*64 + slot];
      #pragma unroll
      for (int i = 0; i < 2; i++)
        #pragma unroll
        for (int j = 0; j < 4; j++)
          acc[i][j] = __builtin_amdgcn_mfma_f32_16x16x32_bf16(af[i], bfr[j], acc[i][j], 0, 0, 0);
    }
  }
  #pragma unroll
  for (int i = 0; i < 2; i++){
    int rbase = m0 + w*32 + i*16 + lk*4;
    #pragma unroll
    for (int j = 0; j < 4; j++){
      int cc = n0 + j*16 + lr;
      #pragma unroll
      for (int jj = 0; jj < 4; jj++){
        int rr = rbase + jj;
        parts[(size_t)bz*QH*DD + (size_t)rr*DD + cc] = f2bf(acc[i][j][jj]);
      }
    }
  }
}

// ---------------- skinny MFMA GEMM: C(64 x N) = A(64 x K) @ Bt(N x K)^T ----------------
// ACT: 0 none, 1 relu, 2 gelu.  RES: 0 store, 1 atomicAdd.  OUTB: bf16 out.
// DOLN: 0 gl16 A, 1 LN(xf) in-block, 2 convert xf in-block.  NG: guard col<N.
// HPB: bf16 copy of cols>=1536.  ZMAP: z-layout store.  ARED: A = sum of 8 bf16 partial slices.
template<int ACT, int RES, int OUTB, int DOLN, int NG, int HPB, int ZMAP = 0, int ARED = 0>
__global__ __launch_bounds__(256) void k_mf64(
    const u16* __restrict__ A, const float* __restrict__ xf,
    const float* __restrict__ g, const float* __restrict__ bb,
    const u16* __restrict__ Bt, const float* __restrict__ bias,
    float* __restrict__ C, u16* __restrict__ Cb, u16* __restrict__ Cb2,
    int N, int K, int kper, int ldc, float alpha)
{
  __shared__ __align__(16) u16 Asl[DOLN ? 64*520 : 64*64];
  __shared__ __align__(16) u16 Bs[64*64];
  int t = threadIdx.x, lane = t & 63, w = t >> 6;
  int lr = lane & 15, lk = lane >> 4;
  int n0 = blockIdx.x*64;
  int ks = blockIdx.y, kbeg = ks*kper;
  int sr8 = t >> 3, sl = t & 7;
  int sw = ((sl ^ (sr8 & 7)) * 8);

  if (DOLN == 1){
    for (int rr = 0; rr < 16; rr++){
      int row = w*16 + rr;
      const float* xr = xf + (size_t)row*DD;
      float4 v0 = *(const float4*)(xr + lane*4);
      float4 v1 = *(const float4*)(xr + 256 + lane*4);
      float s = v0.x+v0.y+v0.z+v0.w + v1.x+v1.y+v1.z+v1.w;
      s = wred_sum(s);
      float mu = s * (1.f/DD);
      float d0=v0.x-mu, d1=v0.y-mu, d2=v0.z-mu, d3=v0.w-mu;
      float e0=v1.x-mu, e1=v1.y-mu, e2=v1.z-mu, e3=v1.w-mu;
      float q = d0*d0+d1*d1+d2*d2+d3*d3 + e0*e0+e1*e1+e2*e2+e3*e3;
      q = wred_sum(q);
      float inv = rsqrtf(q * (1.f/DD) + 1e-5f);
      float4 g0 = *(const float4*)(g + lane*4);
      float4 g1 = *(const float4*)(g + 256 + lane*4);
      float4 b0 = *(const float4*)(bb + lane*4);
      float4 b1 = *(const float4*)(bb + 256 + lane*4);
      u16* dst = &Asl[row*520];
      dst[lane*4+0] = f2bf(d0*inv*g0.x + b0.x);
      dst[lane*4+1] = f2bf(d1*inv*g0.y + b0.y);
      dst[lane*4+2] = f2bf(d2*inv*g0.z + b0.z);
      dst[lane*4+3] = f2bf(d3*inv*g0.w + b0.w);
      dst[256+lane*4+0] = f2bf(e0*inv*g1.x + b1.x);
      dst[256+lane*4+1] = f2bf(e1*inv*g1.y + b1.y);
      dst[256+lane*4+2] = f2bf(e2*inv*g1.z + b1.z);
      dst[256+lane*4+3] = f2bf(e3*inv*g1.w + b1.w);
    }
  } else if (DOLN == 2){
    for (int rr = 0; rr < 16; rr++){
      int row = w*16 + rr;
      const float* xr = xf + (size_t)row*DD;
      float4 v0 = *(const float4*)(xr + lane*4);
      float4 v1 = *(const float4*)(xr + 256 + lane*4);
      u16* dst = &Asl[row*520];
      dst[lane*4+0] = f2bf(v0.x);
      dst[lane*4+1] = f2bf(v0.y);
      dst[lane*4+2] = f2bf(v0.z);
      dst[lane*4+3] = f2bf(v0.w);
      dst[256+lane*4+0] = f2bf(v1.x);
      dst[256+lane*4+1] = f2bf(v1.y);
      dst[256+lane*4+2] = f2bf(v1.z);
      dst[256+lane*4+3] = f2bf(v1.w);
    }
  }

  float4v acc[4];
  float4v z4 = {0.f,0.f,0.f,0.f};
  acc[0]=z4; acc[1]=z4; acc[2]=z4; acc[3]=z4;

  for (int kc = kbeg; kc < kbeg + kper; kc += 64){
    __syncthreads();
    if (ARED){
      // A[row][kc+c] = sum_sp parts[b*8+sp][q*16+h][(kc&511)+c], h = kc>>9
      int row = t >> 2;
      int b_ = row >> 4, q_ = row & 15;
      int c0 = (t & 3) * 16;
      int h_ = kc >> 9;
      const u16* src = A + ((size_t)b_*8)*131072 + (size_t)(q_*16 + h_)*512 + (kc & 511) + c0;
      float s[16];
      #pragma unroll
      for (int i = 0; i < 16; i++) s[i] = 0.f;
      #pragma unroll
      for (int sp = 0; sp < 8; sp++){
        const u16* ps = src + (size_t)sp*131072;
        #pragma unroll
        for (int q4 = 0; q4 < 4; q4++){
          ushort4 gg = *(const ushort4*)(ps + q4*4);
          s[q4*4+0] += bf2f(gg.x); s[q4*4+1] += bf2f(gg.y);
          s[q4*4+2] += bf2f(gg.z); s[q4*4+3] += bf2f(gg.w);
        }
      }
      #pragma unroll
      for (int gr = 0; gr < 2; gr++){
        int dc = (((t & 3)*2 + gr) ^ (row & 7)) * 8;
        ushort4 o0, o1;
        o0.x = f2bf(s[gr*8+0]); o0.y = f2bf(s[gr*8+1]); o0.z = f2bf(s[gr*8+2]); o0.w = f2bf(s[gr*8+3]);
        o1.x = f2bf(s[gr*8+4]); o1.y = f2bf(s[gr*8+5]); o1.z = f2bf(s[gr*8+6]); o1.w = f2bf(s[gr*8+7]);
        *(ushort4*)&Asl[row*64 + dc] = o0;
        *(ushort4*)&Asl[row*64 + dc + 4] = o1;
      }
    } else if (!DOLN){
      gl16(A + (size_t)sr8*K + kc + sw,        (u16*)Asl + 8*t);
      gl16(A + (size_t)(32+sr8)*K + kc + sw,   (u16*)Asl + 2048 + 8*t);
    }
    gl16(Bt + (size_t)(n0+sr8)*K + kc + sw,      (u16*)Bs + 8*t);
    gl16(Bt + (size_t)(n0+32+sr8)*K + kc + sw,   (u16*)Bs + 2048 + 8*t);
    __syncthreads();
    #pragma unroll
    for (int s = 0; s < 2; s++){
      int slot = ((s*4 + lk) ^ (lr & 7)) * 8;
      short8 af;
      if (DOLN) af = *(const short8*)&Asl[(w*16+lr)*520 + kc + s*32 + lk*8];
      else      af = *(const short8*)&Asl[(w*16+lr)*64 + slot];
      #pragma unroll
      for (int nf = 0; nf < 4; nf++){
        short8 bf8 = *(const short8*)&Bs[(nf*16+lr)*64 + slot];
        acc[nf] = __builtin_amdgcn_mfma_f32_16x16x32_bf16(af, bf8, acc[nf], 0, 0, 0);
      }
    }
  }
  #pragma unroll
  for (int nf = 0; nf < 4; nf++){
    int col = n0 + nf*16 + lr;
    float bsv = (bias && ks == 0) ? bias[col] : 0.f;
    #pragma unroll
    for (int jj = 0; jj < 4; jj++){
      int row = w*16 + lk*4 + jj;
      float v = acc[nf][jj]*alpha + bsv;
      if (ACT == 1) v = fmaxf(v, 0.f);
      else if (ACT == 2) v = 0.5f*v*(1.f + tanhf(0.7978845608028654f*(v + 0.044715f*v*v*v)));
      if (NG && col >= N) continue;
      if (ZMAP){
        int b_ = row >> 4, q_ = row & 15, h_ = col >> 9, d_ = col & 511;
        Cb[((size_t)b_*QH + (q_ << 4) + h_)*DD + d_] = f2bf(v);
        continue;
      }
      size_t o = (size_t)row*ldc + col;
      if (OUTB == 1) Cb[o] = f2bf(v);
      else if (RES == 0) C[o] = v;
      else atomicAdd(&C[o], v);
      if (HPB && col >= 1536) Cb2[(size_t)row*DD + (col - 1536)] = f2bf(v);
    }
  }
}

// ---------------- softmax over 4096, bf16 in -> bf16 probs (packed uint IO) ----------------
__global__ __launch_bounds__(256) void k_softmax(const u16* __restrict__ lg, u16* __restrict__ att){
  int row = blockIdx.x, t = threadIdx.x;
  const uint* p = (const uint*)(lg + (size_t)row*TOK);
  uint pv[8]; float v0[8], v1[8]; float mx = -1e30f;
  #pragma unroll
  for (int i = 0; i < 8; i++){
    pv[i] = p[t + i*256];
    v0[i] = bf2f((u16)(pv[i] & 0xFFFF));
    v1[i] = bf2f((u16)(pv[i] >> 16));
    mx = fmaxf(mx, fmaxf(v0[i], v1[i]));
  }
  int lane = t & 63, w = t >> 6;
  for (int o = 32; o; o >>= 1) mx = fmaxf(mx, __shfl_xor(mx, o, 64));
  __shared__ float sm[4]; __shared__ float ssum[4];
  if (lane == 0) sm[w] = mx;
  __syncthreads();
  mx = fmaxf(fmaxf(sm[0], sm[1]), fmaxf(sm[2], sm[3]));
  float s = 0.f;
  #pragma unroll
  for (int i = 0; i < 8; i++){
    v0[i] = expf(v0[i] - mx); v1[i] = expf(v1[i] - mx);
    s += v0[i] + v1[i];
  }
  s = wred_sum(s);
  if (lane == 0) ssum[w] = s;
  __syncthreads();
  s = ssum[0]+ssum[1]+ssum[2]+ssum[3];
  float inv = 1.f / s;
  uint* q = (uint*)(att + (size_t)row*TOK);
  #pragma unroll
  for (int i = 0; i < 8; i++){
    uint lo = f2bf(v0[i]*inv);
    uint hi = f2bf(v1[i]*inv);
    q[t + i*256] = lo | (hi << 16);
  }
}

// ---------------- final heads + Gram-Schmidt + assembly ----------------
__global__ __launch_bounds__(256) void k_final(
    const float* __restrict__ h4, const float* __restrict__ rot6d,
    const float* __restrict__ offW2, const float* __restrict__ offb2,
    const float* __restrict__ dW2, const float* __restrict__ db2,
    const float* __restrict__ sW2, const float* __restrict__ sb2,
    const float* __restrict__ K_cam, const float* __restrict__ useful,
    const float* __restrict__ maskf, const float* __restrict__ colf, const float* __restrict__ rowf,
    float* __restrict__ out)
{
  int bq = blockIdx.x, t = threadIdx.x, b = bq >> 4;
  float po0 = 0.f, po1 = 0.f, pd = 0.f, ps[11];
  #pragma unroll
  for (int j = 0; j < 11; j++) ps[j] = 0.f;
  const float* hrow = h4 + (size_t)bq*2048;
  for (int i = t; i < DD; i += 256){
    float ho = hrow[i];
    float hd = hrow[512 + i];
    float hs = hrow[1024 + i];
    po0 += ho*offW2[i*2]; po1 += ho*offW2[i*2+1];
    pd += hd*dW2[i];
    #pragma unroll
    for (int j = 0; j < 11; j++) ps[j] += hs*sW2[i*11+j];
  }
  __shared__ float sred[4][14];
  __shared__ float sout[14];
  int wv = t >> 6, ln = t & 63;
  float vals[14];
  vals[0] = po0; vals[1] = po1; vals[2] = pd;
  #pragma unroll
  for (int j = 0; j < 11; j++) vals[3+j] = ps[j];
  #pragma unroll
  for (int kk = 0; kk < 14; kk++){
    float r = wred_sum(vals[kk]);
    if (ln == 0) sred[wv][kk] = r;
  }
  __syncthreads();
  if (t < 14) sout[t] = sred[0][t]+sred[1][t]+sred[2][t]+sred[3][t];
  __syncthreads();
  float m = maskf[bq];
  if (t == 0){
    float off0 = sout[0] + offb2[0], off1 = sout[1] + offb2[1];
    float draw = sout[2] + db2[0];
    float l0 = (colf[bq] + 0.5f + off0) * 14.0f;
    float l1 = (rowf[bq] + 0.5f + off1) * 14.0f;
    float fx = K_cam[b*9+0], cx = K_cam[b*9+2], fy = K_cam[b*9+4], cy = K_cam[b*9+5];
    float dist = fx / fmaxf(expf(draw), 1e-5f);
    float tx = (l0 - cx) / fx * dist, ty = (l1 - cy) / fy * dist;
    float* o = out + (size_t)bq*OUTW;
    o[0] = l0*m; o[1] = l1*m; o[2] = off0*m; o[3] = off1*m; o[4] = dist*m;
    o[5] = tx*m; o[6] = ty*m; o[7] = dist*m;
    #pragma unroll
    for (int j = 0; j < 11; j++){ float sp = sout[3+j] + sb2[j]; o[8+j] = m / (1.f + expf(-sp)); }
  }
  if (t < NJ){
    const float* rp = rot6d + (size_t)bq*NROT + t*6;
    float a0 = rp[0], b0 = rp[1], a1 = rp[2], b1 = rp[3], a2 = rp[4], b2 = rp[5];
    float n0 = sqrtf(a0*a0 + a1*a1 + a2*a2);
    float i0 = 1.f / (n0 + 1e-8f);
    float u00 = a0*i0, u01 = a1*i0, u02 = a2*i0;
    float dt = b0*u00 + b1*u01 + b2*u02;
    float v0 = b0 - dt*u00, v1 = b1 - dt*u01, v2 = b2 - dt*u02;
    float n1 = sqrtf(v0*v0 + v1*v1 + v2*v2);
    float i1 = 1.f / (n1 + 1e-8f);
    float u10 = v0*i1, u11 = v1*i1, u12 = v2*i1;
    float u20 = u01*u12 - u02*u11;
    float u21 = u02*u10 - u00*u12;
    float u22 = u00*u11 - u01*u10;
    float um = useful[t], om = 1.f - um;
    float R00 = um*u00 + om, R01 = um*u10,      R02 = um*u20;
    float R10 = um*u01,      R11 = um*u11 + om, R12 = um*u21;
    float R20 = um*u02,      R21 = um*u12,      R22 = um*u22 + om;
    float* o = out + (size_t)bq*OUTW + 19 + t*9;
    o[0] = R00*m; o[1] = R01*m; o[2] = R02*m;
    o[3] = R10*m; o[4] = R11*m; o[5] = R12*m;
    o[6] = R20*m; o[7] = R21*m; o[8] = R22*m;
  }
}

extern "C" void kernel_launch(void* const* d_in, const int* in_sizes, int n_in,
                              void* d_out, int out_size, void* d_ws, size_t ws_size,
                              hipStream_t stream)
{
  const float* feat   = (const float*)d_in[0];
  const float* scores = (const float*)d_in[1];
  const float* K_cam  = (const float*)d_in[2];
  const float* pos_emb= (const float*)d_in[3];
  const float* Wtok   = (const float*)d_in[4];
  const float* btok   = (const float*)d_in[5];
  const float* Wq     = (const float*)d_in[6];
  const float* Wk     = (const float*)d_in[7];
  const float* Wv     = (const float*)d_in[8];
  const float* Wo     = (const float*)d_in[9];
  const float* g1     = (const float*)d_in[10];
  const float* b1n    = (const float*)d_in[11];
  const float* W1     = (const float*)d_in[12];
  const float* bf1    = (const float*)d_in[13];
  const float* W2     = (const float*)d_in[14];
  const float* bf2    = (const float*)d_in[15];
  const float* g2     = (const float*)d_in[16];
  const float* b2n    = (const float*)d_in[17];
  const float* offW1  = (const float*)d_in[18];
  const float* offb1  = (const float*)d_in[19];
  const float* offW2  = (const float*)d_in[20];
  const float* offb2  = (const float*)d_in[21];
  const float* dW1    = (const float*)d_in[22];
  const float* db1    = (const float*)d_in[23];
  const float* dW2    = (const float*)d_in[24];
  const float* db2    = (const float*)d_in[25];
  const float* sW1    = (const float*)d_in[26];
  const float* sb1    = (const float*)d_in[27];
  const float* sW2    = (const float*)d_in[28];
  const float* sb2    = (const float*)d_in[29];
  const float* pW1    = (const float*)d_in[30];
  const float* pb1    = (const float*)d_in[31];
  const float* pW2    = (const float*)d_in[32];
  const float* pb2    = (const float*)d_in[33];
  const float* ibp    = (const float*)d_in[34];
  const float* useful = (const float*)d_in[35];
  float* out = (float*)d_out;

  char* wsp = (char*)d_ws;
  size_t off = 0;
  auto alloc = [&](size_t bytes)->char*{
    char* p = wsp + off;
    off += (bytes + 255) & ~((size_t)255);
    return p;
  };
  int*   t_idx  = (int*)  alloc(BKQ*4);
  float* t_mask = (float*)alloc(BKQ*4);
  float* t_col  = (float*)alloc(BKQ*4);
  float* t_row  = (float*)alloc(BKQ*4);
  u16*   wtokT  = (u16*)  alloc((size_t)DD*CE*2);
  u16*   ctx_bf = (u16*)  alloc((size_t)BB*TOK*DD*2);
  u16*   ctxT_bf= (u16*)  alloc((size_t)BB*TOK*DD*2);
  u16*   ATb    = (u16*)  alloc((size_t)2*8192*DD*2);   // 2 slots
  u16*   WVOb   = (u16*)  alloc((size_t)2*DD*8192*2);   // 2 slots
  u16*   w1T    = (u16*)  alloc((size_t)LL*DD*MM*2);
  u16*   w2T    = (u16*)  alloc((size_t)LL*MM*DD*2);
  u16*   headsT = (u16*)  alloc((size_t)4*DD*DD*2);
  u16*   pw2T   = (u16*)  alloc((size_t)1024*DD*2);
  float* x      = (float*)alloc((size_t)BKQ*DD*4);
  u16*   z_bf   = (u16*)  alloc((size_t)BKQ*HH*DD*2);
  u16*   logits = (u16*)  alloc((size_t)BB*QH*TOK*2);
  u16*   att_bf = (u16*)  alloc((size_t)BB*QH*TOK*2);
  u16*   parts  = (u16*)  alloc((size_t)BB*8*QH*DD*2);
  u16*   mid_bf = (u16*)  alloc((size_t)BKQ*MM*2);
  float* h4     = (float*)alloc((size_t)BKQ*2048*4);
  u16*   hp_bf  = (u16*)  alloc((size_t)BKQ*DD*2);
  float* hb4    = (float*)alloc(2048*4);
  float* cvec2  = (float*)alloc(1024*4);
  float* rot6d  = (float*)alloc((size_t)BKQ*NROT*4);
  if (off > ws_size) return;

  // job table for unified weight transposer (64x32 tiles; R multiple of 64)
  PJobs J;
  int ntl = 0, nj = 0;
  auto addjob = [&](const float* s, u16* d, int R, int C){
    J.s[nj] = s; J.d[nj] = d; J.R[nj] = R; J.C[nj] = C; J.t0[nj] = ntl;
    ntl += (R/64) * ((C+31)/32);
    nj++;
  };
  addjob(Wtok, wtokT, CE, DD);
  for (int l = 0; l < LL; l++) addjob(W1 + (size_t)l*DD*MM, w1T + (size_t)l*MM*DD, DD, MM);
  for (int l = 0; l < LL; l++) addjob(W2 + (size_t)l*MM*DD, w2T + (size_t)l*DD*MM, MM, DD);
  addjob(offW1, headsT,            DD, DD);
  addjob(dW1,   headsT + DD*DD,    DD, DD);
  addjob(sW1,   headsT + 2*DD*DD,  DD, DD);
  addjob(pW1,   headsT + 3*DD*DD,  DD, DD);
  addjob(pW2,   pw2T, DD, NROT);
  J.t0[nj] = ntl; J.njobs = nj; J.ntiles = ntl;

  const size_t ATS = (size_t)8192*DD;   // slot stride
  k_prep_all<<<2048, 256, 0, stream>>>(J, scores, t_idx, t_mask, t_col, t_row,
                                       pW1, pb1, ibp, hb4, offb1, db1, sb1, pb2, cvec2,
                                       Wq, Wk, Wv, Wo, ATb, WVOb);
  k_gemm_emb<<<dim3(DD/128, (BB*TOK)/128, 1), 256, 0, stream>>>(feat, wtokT, ctx_bf, ctxT_bf, btok, pos_emb);
  k_gather2<<<BKQ, 256, 0, stream>>>(ctx_bf, t_idx, x);

  for (int l = 0; l < LL; l++){
    u16* ATl  = ATb  + (size_t)(l & 1)*ATS;
    u16* WVOl = WVOb + (size_t)(l & 1)*ATS;
    u16* ATn  = ATb  + (size_t)((l+1) & 1)*ATS;
    u16* WVOn = WVOb + (size_t)((l+1) & 1)*ATS;
    // z = LN1(x) @ AT^T  (z layout [b][q*16+h][dout])
    k_mf64<0,0,0,1,0,0,1><<<dim3(128,1), 256, 0, stream>>>(
        nullptr, x, g1 + l*DD, b1n + l*DD, ATl, nullptr,
        nullptr, z_bf, nullptr, 8192, DD, DD, DD, 1.f);
    // logits[b] = Z_b @ ctx_b^T -> bf16
    k_gemm_logits<<<dim3(TOK/64, 2, BB), 256, 0, stream>>>(z_bf, ctx_bf, logits);
    k_softmax<<<BB*QH, 256, 0, stream>>>(logits, att_bf);
    // parts[b*8+ks] = att_b @ ctxT_b^T (bf16 partials) + next-layer AT/WVO fold
    if (l < LL-1){
      k_pv_fused<<<dim3(8, 2, 32 + 128), 256, 0, stream>>>(
          att_bf, ctxT_bf, parts,
          Wq + (size_t)(l+1)*DD*DD, Wk + (size_t)(l+1)*DD*DD,
          Wv + (size_t)(l+1)*DD*DD, Wo + (size_t)(l+1)*DD*DD, ATn, WVOn);
    } else {
      k_pv_fused<<<dim3(8, 2, 32), 256, 0, stream>>>(
          att_bf, ctxT_bf, parts, nullptr, nullptr, nullptr, nullptr, nullptr, nullptr);
    }
    // x += (sum_sp parts) @ WVO^T   (K=8192, ksplit=16, atomic; red8 fused into A-staging)
    k_mf64<0,1,0,0,0,0,0,1><<<dim3(8,16), 256, 0, stream>>>(
        parts, nullptr, nullptr, nullptr, WVOl, nullptr,
        x, nullptr, nullptr, DD, 8192, 512, DD, 1.f);
    // mid = gelu(LN2(x) @ W1 + bf1)  -> bf16
    k_mf64<2,0,1,1,0,0,0><<<dim3(MM/64,1), 256, 0, stream>>>(
        nullptr, x, g2 + l*DD, b2n + l*DD, w1T + (size_t)l*DD*MM, bf1 + l*MM,
        nullptr, mid_bf, nullptr, MM, DD, DD, MM, 1.f);
    // x += mid @ W2 + bf2  (ksplit=8, atomic)
    k_mf64<0,1,0,0,0,0,0><<<dim3(8,8), 256, 0, stream>>>(
        mid_bf, nullptr, nullptr, nullptr, w2T + (size_t)l*MM*DD, bf2 + l*DD,
        x, nullptr, nullptr, DD, MM, MM/8, DD, 1.f);
  }

  // heads: h4 = relu(x @ [offW1|dW1|sW1|pW1] + hb4), bf16 copy of pose slice
  k_mf64<1,0,0,2,0,1,0><<<dim3(32,1), 256, 0, stream>>>(
      nullptr, x, nullptr, nullptr, headsT, hb4,
      h4, nullptr, hp_bf, 2048, DD, DD, 2048, 1.f);
  // rot6d = h_p @ pW2 + (pb2 + ibp)
  k_mf64<0,0,0,0,1,0,0><<<dim3(16,1), 256, 0, stream>>>(
      hp_bf, nullptr, nullptr, nullptr, pw2T, cvec2,
      rot6d, nullptr, nullptr, NROT, DD, DD, NROT, 1.f);
  k_final<<<BKQ, 256, 0, stream>>>(h4, rot6d, offW2, offb2, dW2, db2, sW2, sb2,
                                   K_cam, useful, t_mask, t_col, t_row, out);
}

// Round 12
// 899.094 us; speedup vs baseline: 1.1025x; 1.1025x over previous
//
#include <hip/hip_runtime.h>

typedef unsigned int uint;
typedef unsigned short u16;

#define BB 4
#define CE 384
#define DD 512
#define LL 8
#define HH 16
#define MM 2048
#define NJ 163
#define TOK 4096
#define BKQ 64
#define QH 256
#define OUTW 1486
#define NROT 978
#define QKSCALE 0.17677669529663687f

typedef __attribute__((ext_vector_type(8))) short short8;
typedef __attribute__((ext_vector_type(4))) float float4v;

static __device__ __forceinline__ u16 f2bf(float f){
  union { float f; uint u; } c; c.f = f;
  uint u = c.u;
  return (u16)((u + 0x7FFFu + ((u >> 16) & 1u)) >> 16);
}
static __device__ __forceinline__ float bf2f(u16 u){
  union { uint u; float f; } c; c.u = ((uint)u) << 16;
  return c.f;
}
static __device__ __forceinline__ float wred_sum(float v){
  for (int o = 32; o; o >>= 1) v += __shfl_xor(v, o, 64);
  return v;
}
static __device__ __forceinline__ void gl16(const void* g, void* l){
  __builtin_amdgcn_global_load_lds((const __attribute__((address_space(1))) void*)g,
                                   (__attribute__((address_space(3))) void*)l, 16, 0, 0);
}

// ---------------- unified prep: NMS + transposes (64x32) + pose-const + bias ----------------
struct PJobs {
  const float* s[24]; u16* d[24];
  int R[24], C[24], t0[25];
  int njobs, ntiles;
};
__global__ __launch_bounds__(256) void k_prep_all(PJobs J,
    const float* __restrict__ scores,
    int* __restrict__ oidx, float* __restrict__ omask, float* __restrict__ ocol, float* __restrict__ orow,
    const float* __restrict__ pW1, const float* __restrict__ pb1,
    const float* __restrict__ ibp, float* __restrict__ hb4,
    const float* __restrict__ offb1, const float* __restrict__ db1, const float* __restrict__ sb1,
    const float* __restrict__ pb2, float* __restrict__ cvec2)
{
  int bid = blockIdx.x, t = threadIdx.x;
  __shared__ float sraw[4096];
  __shared__ float sv[4]; __shared__ int si[4]; __shared__ int swin;
  __shared__ u16 tb[32][66];

  if (bid < 4){
    // ---- NMS + top-k (exact fp32, stable ties) ----
    int b = bid;
    const float* sp = scores + (size_t)b * 4096;
    for (int i = t; i < 4096; i += 256) sraw[i] = sp[i];
    __syncthreads();
    float v[16];
    #pragma unroll
    for (int j = 0; j < 16; j++){
      int i = t + j*256;
      int r = i >> 6, c = i & 63;
      float mx = -1e30f;
      for (int dr = -1; dr <= 1; dr++){
        int rr = r + dr; if (rr < 0 || rr > 63) continue;
        for (int dc = -1; dc <= 1; dc++){
          int cc = c + dc; if (cc < 0 || cc > 63) continue;
          mx = fmaxf(mx, sraw[rr*64+cc]);
        }
      }
      float s = sraw[i];
      v[j] = (s == mx) ? s : 0.0f;
    }
    int lane = t & 63, wv = t >> 6;
    for (int iter = 0; iter < 16; iter++){
      float best = -1e30f; int bi_ = 1 << 30;
      #pragma unroll
      for (int j = 0; j < 16; j++){
        if (v[j] > best){ best = v[j]; bi_ = t + j*256; }
      }
      #pragma unroll
      for (int o = 32; o; o >>= 1){
        float ov = __shfl_xor(best, o, 64);
        int oi = __shfl_xor(bi_, o, 64);
        if (ov > best || (ov == best && oi < bi_)){ best = ov; bi_ = oi; }
      }
      if (lane == 0){ sv[wv] = best; si[wv] = bi_; }
      __syncthreads();
      if (t == 0){
        float bb = sv[0]; int ii = si[0];
        for (int k = 1; k < 4; k++){
          if (sv[k] > bb || (sv[k] == bb && si[k] < ii)){ bb = sv[k]; ii = si[k]; }
        }
        oidx[b*16+iter] = ii;
        omask[b*16+iter] = (bb >= 0.3f) ? 1.f : 0.f;
        ocol[b*16+iter] = (float)(ii & 63);
        orow[b*16+iter] = (float)(ii >> 6);
        swin = ii;
      }
      __syncthreads();
      int wi = swin;
      if ((wi & 255) == t) v[wi >> 8] = -1e30f;
      __syncthreads();
    }
  } else if (bid < 132){
    int d = (bid - 4)*4 + (t >> 6);
    int ln = t & 63;
    float acc = 0.f;
    for (int i = ln; i < NJ*6; i += 64) acc += ibp[i] * pW1[(size_t)(DD+i)*DD + d];
    acc = wred_sum(acc);
    if (ln == 0) hb4[1536 + d] = acc + pb1[d];
  } else if (bid == 132){
    for (int i = t; i < 1536; i += 256)
      hb4[i] = (i < 512) ? offb1[i] : (i < 1024 ? db1[i-512] : sb1[i-1024]);
    for (int i = t; i < 1024; i += 256)
      cvec2[i] = (i < NJ*6) ? (pb2[i] + ibp[i]) : 0.f;
  }

  // ---- transpose tiles: 64(r) x 32(c), bf16 LDS, packed-uint coalesced writes ----
  for (int g = bid; g < J.ntiles; g += gridDim.x){
    int j = 0;
    while (g >= J.t0[j+1]) j++;
    int ti = g - J.t0[j];
    int C_ = J.C[j], R_ = J.R[j];
    int tC = (C_ + 31) >> 5;
    int ry = ti / tC, cx = ti - ry*tC;
    int r0 = ry*64, c0 = cx*32;
    int tx = t & 31, ty = t >> 5;
    const float* src = J.s[j]; u16* dst = J.d[j];
    __syncthreads();
    #pragma unroll
    for (int i = 0; i < 8; i++){
      int r = ty + i*8;
      float v = 0.f;
      if (c0+tx < C_) v = src[(size_t)(r0+r)*C_ + c0+tx];
      tb[tx][r] = f2bf(v);
    }
    __syncthreads();
    #pragma unroll
    for (int p = 0; p < 4; p++){
      int c = (t >> 5) + p*8;
      int rr = t & 31;
      if (c0 + c < C_){
        uint val = (uint)tb[c][2*rr] | ((uint)tb[c][2*rr+1] << 16);
        *(uint*)&dst[(size_t)(c0+c)*R_ + r0 + rr*2] = val;
      }
    }
  }
}

// ---------------- AT/WVO prep, per layer (2048 blocks) ----------------
__global__ __launch_bounds__(256) void k_wqkvo(const float* __restrict__ wq, const float* __restrict__ wk,
    const float* __restrict__ wv, const float* __restrict__ wo,
    u16* __restrict__ AT, u16* __restrict__ WVOT)
{
  __shared__ __align__(16) u16 As[2560];
  __shared__ __align__(16) u16 Bs[2560];
  int t = threadIdx.x;
  int lane = t & 63, w = t >> 6, lr = lane & 15, lk = lane >> 4;
  float4v acc[4];
  float4v z4 = {0.f,0.f,0.f,0.f};
  acc[0]=z4; acc[1]=z4; acc[2]=z4; acc[3]=z4;
  if (blockIdx.x < 1024){
    int id = blockIdx.x;
    int rt = id & 127, dt = id >> 7;
    int h = rt >> 3, dout0 = (rt & 7)*64, din0 = dt*64;
    int r = t >> 2, c0 = (t & 3)*8;
    {
      float4 u0 = *(const float4*)(wk + (size_t)(dout0+r)*DD + h*32 + c0);
      float4 u1 = *(const float4*)(wk + (size_t)(dout0+r)*DD + h*32 + c0 + 4);
      u16* d = As + r*40 + c0;
      d[0]=f2bf(u0.x); d[1]=f2bf(u0.y); d[2]=f2bf(u0.z); d[3]=f2bf(u0.w);
      d[4]=f2bf(u1.x); d[5]=f2bf(u1.y); d[6]=f2bf(u1.z); d[7]=f2bf(u1.w);
      float4 v0 = *(const float4*)(wq + (size_t)(din0+r)*DD + h*32 + c0);
      float4 v1 = *(const float4*)(wq + (size_t)(din0+r)*DD + h*32 + c0 + 4);
      u16* e = Bs + r*40 + c0;
      e[0]=f2bf(v0.x); e[1]=f2bf(v0.y); e[2]=f2bf(v0.z); e[3]=f2bf(v0.w);
      e[4]=f2bf(v1.x); e[5]=f2bf(v1.y); e[6]=f2bf(v1.z); e[7]=f2bf(v1.w);
    }
    __syncthreads();
    short8 af = *(const short8*)&As[(w*16+lr)*40 + lk*8];
    #pragma unroll
    for (int nf = 0; nf < 4; nf++){
      short8 bf8 = *(const short8*)&Bs[(nf*16+lr)*40 + lk*8];
      acc[nf] = __builtin_amdgcn_mfma_f32_16x16x32_bf16(af, bf8, acc[nf], 0, 0, 0);
    }
    #pragma unroll
    for (int nf = 0; nf < 4; nf++){
      #pragma unroll
      for (int jj = 0; jj < 4; jj++){
        int row = w*16 + lk*4 + jj;
        AT[(size_t)(h*512 + dout0 + row)*DD + din0 + nf*16 + lr] = f2bf(acc[nf][jj]*QKSCALE);
      }
    }
  } else {
    int id = blockIdx.x - 1024;
    int ct = id & 127, dt = id >> 7;
    int h = ct >> 3, Dc0 = (ct & 7)*64, dout0 = dt*64;
    {
      int c = t >> 3, d8 = (t & 7)*8;
      float4 a0 = *(const float4*)(wo + (size_t)(h*32+c)*DD + dout0 + d8);
      float4 a1 = *(const float4*)(wo + (size_t)(h*32+c)*DD + dout0 + d8 + 4);
      As[(d8+0)*40 + c] = f2bf(a0.x);
      As[(d8+1)*40 + c] = f2bf(a0.y);
      As[(d8+2)*40 + c] = f2bf(a0.z);
      As[(d8+3)*40 + c] = f2bf(a0.w);
      As[(d8+4)*40 + c] = f2bf(a1.x);
      As[(d8+5)*40 + c] = f2bf(a1.y);
      As[(d8+6)*40 + c] = f2bf(a1.z);
      As[(d8+7)*40 + c] = f2bf(a1.w);
      int r = t >> 2, c0 = (t & 3)*8;
      float4 v0 = *(const float4*)(wv + (size_t)(Dc0+r)*DD + h*32 + c0);
      float4 v1 = *(const float4*)(wv + (size_t)(Dc0+r)*DD + h*32 + c0 + 4);
      u16* e = Bs + r*40 + c0;
      e[0]=f2bf(v0.x); e[1]=f2bf(v0.y); e[2]=f2bf(v0.z); e[3]=f2bf(v0.w);
      e[4]=f2bf(v1.x); e[5]=f2bf(v1.y); e[6]=f2bf(v1.z); e[7]=f2bf(v1.w);
    }
    __syncthreads();
    short8 af = *(const short8*)&As[(w*16+lr)*40 + lk*8];
    #pragma unroll
    for (int nf = 0; nf < 4; nf++){
      short8 bf8 = *(const short8*)&Bs[(nf*16+lr)*40 + lk*8];
      acc[nf] = __builtin_amdgcn_mfma_f32_16x16x32_bf16(af, bf8, acc[nf], 0, 0, 0);
    }
    #pragma unroll
    for (int nf = 0; nf < 4; nf++){
      #pragma unroll
      for (int jj = 0; jj < 4; jj++){
        int row = w*16 + lk*4 + jj;
        WVOT[(size_t)(dout0 + row)*8192 + h*512 + Dc0 + nf*16 + lr] = f2bf(acc[nf][jj]);
      }
    }
  }
}

// ---------------- reduce 8 PV split-K bf16 partials -> c_flat bf16 [bq][h*512+Dc] ----------------
__global__ __launch_bounds__(256) void k_red8(const u16* __restrict__ parts, u16* __restrict__ cf){
  int i4 = blockIdx.x*256 + threadIdx.x;
  int elem = i4*4;
  int row = elem >> 13, col = elem & 8191;
  int b = row >> 4, q = row & 15, h = col >> 9, Dc = col & 511;
  const u16* src = parts + ((size_t)b*8)*131072 + (size_t)(q*16+h)*512 + Dc;
  float s0 = 0.f, s1 = 0.f, s2 = 0.f, s3 = 0.f;
  #pragma unroll
  for (int ks = 0; ks < 8; ks++){
    ushort4 g = *(const ushort4*)(src + (size_t)ks*131072);
    s0 += bf2f(g.x); s1 += bf2f(g.y); s2 += bf2f(g.z); s3 += bf2f(g.w);
  }
  ushort4 o;
  o.x = f2bf(s0); o.y = f2bf(s1); o.z = f2bf(s2); o.w = f2bf(s3);
  *(ushort4*)&cf[(size_t)row*8192 + col] = o;
}

// ---------------- ctx embed GEMM: ctx = feat(fp32) @ wtokT^T + btok + pos_emb -> bf16 ctx + ctxT ----------------
__global__ __launch_bounds__(256) void k_gemm_emb(
    const float* __restrict__ feat, const u16* __restrict__ Bt,
    u16* __restrict__ ctx, u16* __restrict__ ctxT,
    const float* __restrict__ ep1, const float* __restrict__ ep2)
{
  __shared__ __align__(16) u16 SM[16640];
  u16* As = SM;
  u16* Bs = SM + 8192;
  int m0 = blockIdx.y*128, n0 = blockIdx.x*128;
  int t = threadIdx.x, lane = t & 63, wave = t >> 6;
  int wr = wave >> 1, wc = wave & 1;
  int lr = lane & 15, lk = lane >> 4;
  int sr8 = t >> 3, sl = t & 7;
  int sw = ((sl ^ (sr8 & 7)) * 8);
  float4v acc[4][4];
  float4v z4 = {0.f, 0.f, 0.f, 0.f};
  #pragma unroll
  for (int i = 0; i < 4; i++)
    #pragma unroll
    for (int j = 0; j < 4; j++) acc[i][j] = z4;
  for (int kt = 0; kt < CE; kt += 64){
    __syncthreads();
    #pragma unroll
    for (int p = 0; p < 8; p++){
      int r = (t >> 4) + p*16, f4 = t & 15;
      float4 v = *(const float4*)&feat[(size_t)(m0+r)*CE + kt + f4*4];
      int dc = ((f4 >> 1) ^ (r & 7))*8 + (f4 & 1)*4;
      ushort4 o; o.x = f2bf(v.x); o.y = f2bf(v.y); o.z = f2bf(v.z); o.w = f2bf(v.w);
      *(ushort4*)&As[r*64 + dc] = o;
    }
    #pragma unroll
    for (int rg = 0; rg < 4; rg++)
      gl16(Bt + (size_t)(n0 + rg*32 + sr8)*CE + kt + sw, Bs + rg*2048 + 8*t);
    __syncthreads();
    #pragma unroll
    for (int s = 0; s < 2; s++){
      int slot = ((s*4 + lk) ^ (lr & 7)) * 8;
      short8 af[4], bfr[4];
      #pragma unroll
      for (int i = 0; i < 4; i++) af[i] = *(const short8*)&As[(wr*64 + i*16 + lr)*64 + slot];
      #pragma unroll
      for (int j = 0; j < 4; j++) bfr[j] = *(const short8*)&Bs[(wc*64 + j*16 + lr)*64 + slot];
      #pragma unroll
      for (int i = 0; i < 4; i++)
        #pragma unroll
        for (int j = 0; j < 4; j++)
          acc[i][j] = __builtin_amdgcn_mfma_f32_16x16x32_bf16(af[i], bfr[j], acc[i][j], 0, 0, 0);
    }
  }
  __syncthreads();
  #pragma unroll
  for (int i = 0; i < 4; i++){
    int rbase = m0 + wr*64 + i*16 + lk*4;
    #pragma unroll
    for (int j = 0; j < 4; j++){
      int cc = n0 + wc*64 + j*16 + lr;
      #pragma unroll
      for (int jj = 0; jj < 4; jj++){
        int rr = rbase + jj;
        float vv = acc[i][j][jj] + ep1[cc] + ep2[(size_t)(rr & 4095)*DD + cc];
        u16 bv = f2bf(vv);
        ctx[(size_t)rr*DD + cc] = bv;
        SM[(cc - n0)*130 + (rr - m0)] = bv;
      }
    }
  }
  __syncthreads();
  int b = m0 >> 12, tok0 = m0 & 4095;
  int tx = t & 63, ty = t >> 6;
  #pragma unroll 4
  for (int it = 0; it < 32; it++){
    int c = ty*32 + it;
    uint vv = *(const uint*)&SM[c*130 + tx*2];
    *(uint*)&ctxT[((size_t)b*DD + n0 + c)*TOK + tok0 + tx*2] = vv;
  }
}

// ---------------- gather x0 from ctx rows (bf16 -> fp32) ----------------
__global__ __launch_bounds__(256) void k_gather2(const u16* __restrict__ ctx, const int* __restrict__ oidx,
    float* __restrict__ x)
{
  int bq = blockIdx.x, t = threadIdx.x;
  int b = bq >> 4, tok = oidx[bq];
  uint v = ((const uint*)(ctx + ((size_t)b*TOK + tok)*DD))[t];
  float2 o; o.x = bf2f((u16)(v & 0xFFFF)); o.y = bf2f((u16)(v >> 16));
  *(float2*)&x[(size_t)bq*DD + t*2] = o;
}

// ---------------- MFMA GEMM, 128(M) x 64(N) tiles: C = A(MxK) @ Bt(NxK)^T ----------------
// EPI 1: bf16 store batch slice.  EPI 2: bf16 store slice bz (split-K partials).
template<int EPI>
__global__ __launch_bounds__(256) void k_gemm_bt64(
    const u16* __restrict__ A, const u16* __restrict__ Bt,
    float* __restrict__ C, u16* __restrict__ Cb,
    int Kslice, int lda, int ldb, int ldc,
    long sA, long sB, long sC, int ksplit)
{
  int bz = blockIdx.z;
  int batch = bz / ksplit, ks = bz - batch*ksplit;
  const u16* Ab = A + (size_t)batch*sA + (size_t)ks*Kslice;
  const u16* Bb = Bt + (size_t)batch*sB + (size_t)ks*Kslice;
  int m0 = blockIdx.y*128, n0 = blockIdx.x*64;
  __shared__ __align__(16) u16 As[128*64];
  __shared__ __align__(16) u16 Bs[64*64];
  int t = threadIdx.x, lane = t & 63, w = t >> 6;
  int lr = lane & 15, lk = lane >> 4;
  int sr8 = t >> 3, sl = t & 7;
  int sw = ((sl ^ (sr8 & 7)) * 8);
  float4v acc[2][4];
  float4v z4 = {0.f,0.f,0.f,0.f};
  #pragma unroll
  for (int i = 0; i < 2; i++)
    #pragma unroll
    for (int j = 0; j < 4; j++) acc[i][j] = z4;

  for (int kt = 0; kt < Kslice; kt += 64){
    __syncthreads();
    #pragma unroll
    for (int rg = 0; rg < 4; rg++)
      gl16(Ab + (size_t)(m0 + rg*32 + sr8)*lda + kt + sw, As + rg*2048 + 8*t);
    #pragma unroll
    for (int rg = 0; rg < 2; rg++)
      gl16(Bb + (size_t)(n0 + rg*32 + sr8)*ldb + kt + sw, Bs + rg*2048 + 8*t);
    __syncthreads();
    #pragma unroll
    for (int s = 0; s < 2; s++){
      int slot = ((s*4 + lk) ^ (lr & 7)) * 8;
      short8 af[2], bfr[4];
      #pragma unroll
      for (int i = 0; i < 2; i++) af[i] = *(const short8*)&As[(w*32 + i*16 + lr)*64 + slot];
      #pragma unroll
      for (int j = 0; j < 4; j++) bfr[j] = *(const short8*)&Bs[(j*16 + lr)*64 + slot];
      #pragma unroll
      for (int i = 0; i < 2; i++)
        #pragma unroll
        for (int j = 0; j < 4; j++)
          acc[i][j] = __builtin_amdgcn_mfma_f32_16x16x32_bf16(af[i], bfr[j], acc[i][j], 0, 0, 0);
    }
  }
  #pragma unroll
  for (int i = 0; i < 2; i++){
    int rbase = m0 + w*32 + i*16 + lk*4;
    #pragma unroll
    for (int j = 0; j < 4; j++){
      int cc = n0 + j*16 + lr;
      #pragma unroll
      for (int jj = 0; jj < 4; jj++){
        int rr = rbase + jj;
        if (EPI == 1) Cb[(size_t)batch*sC + (size_t)rr*ldc + cc] = f2bf(acc[i][j][jj]);
        else Cb[(size_t)bz*sC + (size_t)rr*ldc + cc] = f2bf(acc[i][j][jj]);
      }
    }
  }
}

// ---------------- skinny MFMA GEMM: C(64 x N) = A(64 x K) @ Bt(N x K)^T ----------------
// ACT: 0 none, 1 relu, 2 gelu.  RES: 0 store, 1 atomicAdd.  OUTB: bf16 out.
// DOLN: 0 gl16 A, 1 LN(xf) in-block, 2 convert xf in-block.  NG: guard col<N.
// HPB: bf16 copy of cols>=1536.  ZMAP: z-layout store.
template<int ACT, int RES, int OUTB, int DOLN, int NG, int HPB, int ZMAP = 0>
__global__ __launch_bounds__(256) void k_mf64(
    const u16* __restrict__ A, const float* __restrict__ xf,
    const float* __restrict__ g, const float* __restrict__ bb,
    const u16* __restrict__ Bt, const float* __restrict__ bias,
    float* __restrict__ C, u16* __restrict__ Cb, u16* __restrict__ Cb2,
    int N, int K, int kper, int ldc, float alpha)
{
  __shared__ __align__(16) u16 Asl[DOLN ? 64*520 : 64*64];
  __shared__ __align__(16) u16 Bs[64*64];
  int t = threadIdx.x, lane = t & 63, w = t >> 6;
  int lr = lane & 15, lk = lane >> 4;
  int n0 = blockIdx.x*64;
  int ks = blockIdx.y, kbeg = ks*kper;
  int sr8 = t >> 3, sl = t & 7;
  int sw = ((sl ^ (sr8 & 7)) * 8);

  if (DOLN == 1){
    for (int rr = 0; rr < 16; rr++){
      int row = w*16 + rr;
      const float* xr = xf + (size_t)row*DD;
      float4 v0 = *(const float4*)(xr + lane*4);
      float4 v1 = *(const float4*)(xr + 256 + lane*4);
      float s = v0.x+v0.y+v0.z+v0.w + v1.x+v1.y+v1.z+v1.w;
      s = wred_sum(s);
      float mu = s * (1.f/DD);
      float d0=v0.x-mu, d1=v0.y-mu, d2=v0.z-mu, d3=v0.w-mu;
      float e0=v1.x-mu, e1=v1.y-mu, e2=v1.z-mu, e3=v1.w-mu;
      float q = d0*d0+d1*d1+d2*d2+d3*d3 + e0*e0+e1*e1+e2*e2+e3*e3;
      q = wred_sum(q);
      float inv = rsqrtf(q * (1.f/DD) + 1e-5f);
      float4 g0 = *(const float4*)(g + lane*4);
      float4 g1 = *(const float4*)(g + 256 + lane*4);
      float4 b0 = *(const float4*)(bb + lane*4);
      float4 b1 = *(const float4*)(bb + 256 + lane*4);
      u16* dst = &Asl[row*520];
      dst[lane*4+0] = f2bf(d0*inv*g0.x + b0.x);
      dst[lane*4+1] = f2bf(d1*inv*g0.y + b0.y);
      dst[lane*4+2] = f2bf(d2*inv*g0.z + b0.z);
      dst[lane*4+3] = f2bf(d3*inv*g0.w + b0.w);
      dst[256+lane*4+0] = f2bf(e0*inv*g1.x + b1.x);
      dst[256+lane*4+1] = f2bf(e1*inv*g1.y + b1.y);
      dst[256+lane*4+2] = f2bf(e2*inv*g1.z + b1.z);
      dst[256+lane*4+3] = f2bf(e3*inv*g1.w + b1.w);
    }
  } else if (DOLN == 2){
    for (int rr = 0; rr < 16; rr++){
      int row = w*16 + rr;
      const float* xr = xf + (size_t)row*DD;
      float4 v0 = *(const float4*)(xr + lane*4);
      float4 v1 = *(const float4*)(xr + 256 + lane*4);
      u16* dst = &Asl[row*520];
      dst[lane*4+0] = f2bf(v0.x);
      dst[lane*4+1] = f2bf(v0.y);
      dst[lane*4+2] = f2bf(v0.z);
      dst[lane*4+3] = f2bf(v0.w);
      dst[256+lane*4+0] = f2bf(v1.x);
      dst[256+lane*4+1] = f2bf(v1.y);
      dst[256+lane*4+2] = f2bf(v1.z);
      dst[256+lane*4+3] = f2bf(v1.w);
    }
  }

  float4v acc[4];
  float4v z4 = {0.f,0.f,0.f,0.f};
  acc[0]=z4; acc[1]=z4; acc[2]=z4; acc[3]=z4;

  for (int kc = kbeg; kc < kbeg + kper; kc += 64){
    __syncthreads();
    if (!DOLN){
      gl16(A + (size_t)sr8*K + kc + sw,        (u16*)Asl + 8*t);
      gl16(A + (size_t)(32+sr8)*K + kc + sw,   (u16*)Asl + 2048 + 8*t);
    }
    gl16(Bt + (size_t)(n0+sr8)*K + kc + sw,      (u16*)Bs + 8*t);
    gl16(Bt + (size_t)(n0+32+sr8)*K + kc + sw,   (u16*)Bs + 2048 + 8*t);
    __syncthreads();
    #pragma unroll
    for (int s = 0; s < 2; s++){
      int slot = ((s*4 + lk) ^ (lr & 7)) * 8;
      short8 af;
      if (DOLN) af = *(const short8*)&Asl[(w*16+lr)*520 + kc + s*32 + lk*8];
      else      af = *(const short8*)&Asl[(w*16+lr)*64 + slot];
      #pragma unroll
      for (int nf = 0; nf < 4; nf++){
        short8 bf8 = *(const short8*)&Bs[(nf*16+lr)*64 + slot];
        acc[nf] = __builtin_amdgcn_mfma_f32_16x16x32_bf16(af, bf8, acc[nf], 0, 0, 0);
      }
    }
  }
  #pragma unroll
  for (int nf = 0; nf < 4; nf++){
    int col = n0 + nf*16 + lr;
    float bsv = (bias && ks == 0) ? bias[col] : 0.f;
    #pragma unroll
    for (int jj = 0; jj < 4; jj++){
      int row = w*16 + lk*4 + jj;
      float v = acc[nf][jj]*alpha + bsv;
      if (ACT == 1) v = fmaxf(v, 0.f);
      else if (ACT == 2) v = 0.5f*v*(1.f + tanhf(0.7978845608028654f*(v + 0.044715f*v*v*v)));
      if (NG && col >= N) continue;
      if (ZMAP){
        int b_ = row >> 4, q_ = row & 15, h_ = col >> 9, d_ = col & 511;
        Cb[((size_t)b_*QH + (q_ << 4) + h_)*DD + d_] = f2bf(v);
        continue;
      }
      size_t o = (size_t)row*ldc + col;
      if (OUTB == 1) Cb[o] = f2bf(v);
      else if (RES == 0) C[o] = v;
      else atomicAdd(&C[o], v);
      if (HPB && col >= 1536) Cb2[(size_t)row*DD + (col - 1536)] = f2bf(v);
    }
  }
}

// ---------------- softmax over 4096, bf16 in -> bf16 probs (packed uint IO) ----------------
__global__ __launch_bounds__(256) void k_softmax(const u16* __restrict__ lg, u16* __restrict__ att){
  int row = blockIdx.x, t = threadIdx.x;
  const uint* p = (const uint*)(lg + (size_t)row*TOK);
  uint pv[8]; float v0[8], v1[8]; float mx = -1e30f;
  #pragma unroll
  for (int i = 0; i < 8; i++){
    pv[i] = p[t + i*256];
    v0[i] = bf2f((u16)(pv[i] & 0xFFFF));
    v1[i] = bf2f((u16)(pv[i] >> 16));
    mx = fmaxf(mx, fmaxf(v0[i], v1[i]));
  }
  int lane = t & 63, w = t >> 6;
  for (int o = 32; o; o >>= 1) mx = fmaxf(mx, __shfl_xor(mx, o, 64));
  __shared__ float sm[4]; __shared__ float ssum[4];
  if (lane == 0) sm[w] = mx;
  __syncthreads();
  mx = fmaxf(fmaxf(sm[0], sm[1]), fmaxf(sm[2], sm[3]));
  float s = 0.f;
  #pragma unroll
  for (int i = 0; i < 8; i++){
    v0[i] = expf(v0[i] - mx); v1[i] = expf(v1[i] - mx);
    s += v0[i] + v1[i];
  }
  s = wred_sum(s);
  if (lane == 0) ssum[w] = s;
  __syncthreads();
  s = ssum[0]+ssum[1]+ssum[2]+ssum[3];
  float inv = 1.f / s;
  uint* q = (uint*)(att + (size_t)row*TOK);
  #pragma unroll
  for (int i = 0; i < 8; i++){
    uint lo = f2bf(v0[i]*inv);
    uint hi = f2bf(v1[i]*inv);
    q[t + i*256] = lo | (hi << 16);
  }
}

// ---------------- final heads + Gram-Schmidt + assembly ----------------
__global__ __launch_bounds__(256) void k_final(
    const float* __restrict__ h4, const float* __restrict__ rot6d,
    const float* __restrict__ offW2, const float* __restrict__ offb2,
    const float* __restrict__ dW2, const float* __restrict__ db2,
    const float* __restrict__ sW2, const float* __restrict__ sb2,
    const float* __restrict__ K_cam, const float* __restrict__ useful,
    const float* __restrict__ maskf, const float* __restrict__ colf, const float* __restrict__ rowf,
    float* __restrict__ out)
{
  int bq = blockIdx.x, t = threadIdx.x, b = bq >> 4;
  float po0 = 0.f, po1 = 0.f, pd = 0.f, ps[11];
  #pragma unroll
  for (int j = 0; j < 11; j++) ps[j] = 0.f;
  const float* hrow = h4 + (size_t)bq*2048;
  for (int i = t; i < DD; i += 256){
    float ho = hrow[i];
    float hd = hrow[512 + i];
    float hs = hrow[1024 + i];
    po0 += ho*offW2[i*2]; po1 += ho*offW2[i*2+1];
    pd += hd*dW2[i];
    #pragma unroll
    for (int j = 0; j < 11; j++) ps[j] += hs*sW2[i*11+j];
  }
  __shared__ float sred[4][14];
  __shared__ float sout[14];
  int wv = t >> 6, ln = t & 63;
  float vals[14];
  vals[0] = po0; vals[1] = po1; vals[2] = pd;
  #pragma unroll
  for (int j = 0; j < 11; j++) vals[3+j] = ps[j];
  #pragma unroll
  for (int kk = 0; kk < 14; kk++){
    float r = wred_sum(vals[kk]);
    if (ln == 0) sred[wv][kk] = r;
  }
  __syncthreads();
  if (t < 14) sout[t] = sred[0][t]+sred[1][t]+sred[2][t]+sred[3][t];
  __syncthreads();
  float m = maskf[bq];
  if (t == 0){
    float off0 = sout[0] + offb2[0], off1 = sout[1] + offb2[1];
    float draw = sout[2] + db2[0];
    float l0 = (colf[bq] + 0.5f + off0) * 14.0f;
    float l1 = (rowf[bq] + 0.5f + off1) * 14.0f;
    float fx = K_cam[b*9+0], cx = K_cam[b*9+2], fy = K_cam[b*9+4], cy = K_cam[b*9+5];
    float dist = fx / fmaxf(expf(draw), 1e-5f);
    float tx = (l0 - cx) / fx * dist, ty = (l1 - cy) / fy * dist;
    float* o = out + (size_t)bq*OUTW;
    o[0] = l0*m; o[1] = l1*m; o[2] = off0*m; o[3] = off1*m; o[4] = dist*m;
    o[5] = tx*m; o[6] = ty*m; o[7] = dist*m;
    #pragma unroll
    for (int j = 0; j < 11; j++){ float sp = sout[3+j] + sb2[j]; o[8+j] = m / (1.f + expf(-sp)); }
  }
  if (t < NJ){
    const float* rp = rot6d + (size_t)bq*NROT + t*6;
    float a0 = rp[0], b0 = rp[1], a1 = rp[2], b1 = rp[3], a2 = rp[4], b2 = rp[5];
    float n0 = sqrtf(a0*a0 + a1*a1 + a2*a2);
    float i0 = 1.f / (n0 + 1e-8f);
    float u00 = a0*i0, u01 = a1*i0, u02 = a2*i0;
    float dt = b0*u00 + b1*u01 + b2*u02;
    float v0 = b0 - dt*u00, v1 = b1 - dt*u01, v2 = b2 - dt*u02;
    float n1 = sqrtf(v0*v0 + v1*v1 + v2*v2);
    float i1 = 1.f / (n1 + 1e-8f);
    float u10 = v0*i1, u11 = v1*i1, u12 = v2*i1;
    float u20 = u01*u12 - u02*u11;
    float u21 = u02*u10 - u00*u12;
    float u22 = u00*u11 - u01*u10;
    float um = useful[t], om = 1.f - um;
    float R00 = um*u00 + om, R01 = um*u10,      R02 = um*u20;
    float R10 = um*u01,      R11 = um*u11 + om, R12 = um*u21;
    float R20 = um*u02,      R21 = um*u12,      R22 = um*u22 + om;
    float* o = out + (size_t)bq*OUTW + 19 + t*9;
    o[0] = R00*m; o[1] = R01*m; o[2] = R02*m;
    o[3] = R10*m; o[4] = R11*m; o[5] = R12*m;
    o[6] = R20*m; o[7] = R21*m; o[8] = R22*m;
  }
}

extern "C" void kernel_launch(void* const* d_in, const int* in_sizes, int n_in,
                              void* d_out, int out_size, void* d_ws, size_t ws_size,
                              hipStream_t stream)
{
  const float* feat   = (const float*)d_in[0];
  const float* scores = (const float*)d_in[1];
  const float* K_cam  = (const float*)d_in[2];
  const float* pos_emb= (const float*)d_in[3];
  const float* Wtok   = (const float*)d_in[4];
  const float* btok   = (const float*)d_in[5];
  const float* Wq     = (const float*)d_in[6];
  const float* Wk     = (const float*)d_in[7];
  const float* Wv     = (const float*)d_in[8];
  const float* Wo     = (const float*)d_in[9];
  const float* g1     = (const float*)d_in[10];
  const float* b1n    = (const float*)d_in[11];
  const float* W1     = (const float*)d_in[12];
  const float* bf1    = (const float*)d_in[13];
  const float* W2     = (const float*)d_in[14];
  const float* bf2    = (const float*)d_in[15];
  const float* g2     = (const float*)d_in[16];
  const float* b2n    = (const float*)d_in[17];
  const float* offW1  = (const float*)d_in[18];
  const float* offb1  = (const float*)d_in[19];
  const float* offW2  = (const float*)d_in[20];
  const float* offb2  = (const float*)d_in[21];
  const float* dW1    = (const float*)d_in[22];
  const float* db1    = (const float*)d_in[23];
  const float* dW2    = (const float*)d_in[24];
  const float* db2    = (const float*)d_in[25];
  const float* sW1    = (const float*)d_in[26];
  const float* sb1    = (const float*)d_in[27];
  const float* sW2    = (const float*)d_in[28];
  const float* sb2    = (const float*)d_in[29];
  const float* pW1    = (const float*)d_in[30];
  const float* pb1    = (const float*)d_in[31];
  const float* pW2    = (const float*)d_in[32];
  const float* pb2    = (const float*)d_in[33];
  const float* ibp    = (const float*)d_in[34];
  const float* useful = (const float*)d_in[35];
  float* out = (float*)d_out;

  char* wsp = (char*)d_ws;
  size_t off = 0;
  auto alloc = [&](size_t bytes)->char*{
    char* p = wsp + off;
    off += (bytes + 255) & ~((size_t)255);
    return p;
  };
  int*   t_idx  = (int*)  alloc(BKQ*4);
  float* t_mask = (float*)alloc(BKQ*4);
  float* t_col  = (float*)alloc(BKQ*4);
  float* t_row  = (float*)alloc(BKQ*4);
  u16*   wtokT  = (u16*)  alloc((size_t)DD*CE*2);
  u16*   ctx_bf = (u16*)  alloc((size_t)BB*TOK*DD*2);
  u16*   ctxT_bf= (u16*)  alloc((size_t)BB*TOK*DD*2);
  u16*   ATb    = (u16*)  alloc((size_t)8192*DD*2);
  u16*   WVOb   = (u16*)  alloc((size_t)DD*8192*2);
  u16*   w1T    = (u16*)  alloc((size_t)LL*DD*MM*2);
  u16*   w2T    = (u16*)  alloc((size_t)LL*MM*DD*2);
  u16*   headsT = (u16*)  alloc((size_t)4*DD*DD*2);
  u16*   pw2T   = (u16*)  alloc((size_t)1024*DD*2);
  float* x      = (float*)alloc((size_t)BKQ*DD*4);
  u16*   z_bf   = (u16*)  alloc((size_t)BKQ*HH*DD*2);
  u16*   logits = (u16*)  alloc((size_t)BB*QH*TOK*2);
  u16*   att_bf = (u16*)  alloc((size_t)BB*QH*TOK*2);
  u16*   parts  = (u16*)  alloc((size_t)BB*8*QH*DD*2);
  u16*   c_flat = (u16*)  alloc((size_t)BKQ*8192*2);
  u16*   mid_bf = (u16*)  alloc((size_t)BKQ*MM*2);
  float* h4     = (float*)alloc((size_t)BKQ*2048*4);
  u16*   hp_bf  = (u16*)  alloc((size_t)BKQ*DD*2);
  float* hb4    = (float*)alloc(2048*4);
  float* cvec2  = (float*)alloc(1024*4);
  float* rot6d  = (float*)alloc((size_t)BKQ*NROT*4);
  if (off > ws_size) return;

  // job table for unified weight transposer (64x32 tiles; R multiple of 64)
  PJobs J;
  int ntl = 0, nj = 0;
  auto addjob = [&](const float* s, u16* d, int R, int C){
    J.s[nj] = s; J.d[nj] = d; J.R[nj] = R; J.C[nj] = C; J.t0[nj] = ntl;
    ntl += (R/64) * ((C+31)/32);
    nj++;
  };
  addjob(Wtok, wtokT, CE, DD);
  for (int l = 0; l < LL; l++) addjob(W1 + (size_t)l*DD*MM, w1T + (size_t)l*MM*DD, DD, MM);
  for (int l = 0; l < LL; l++) addjob(W2 + (size_t)l*MM*DD, w2T + (size_t)l*DD*MM, MM, DD);
  addjob(offW1, headsT,            DD, DD);
  addjob(dW1,   headsT + DD*DD,    DD, DD);
  addjob(sW1,   headsT + 2*DD*DD,  DD, DD);
  addjob(pW1,   headsT + 3*DD*DD,  DD, DD);
  addjob(pW2,   pw2T, DD, NROT);
  J.t0[nj] = ntl; J.njobs = nj; J.ntiles = ntl;

  k_prep_all<<<2048, 256, 0, stream>>>(J, scores, t_idx, t_mask, t_col, t_row,
                                       pW1, pb1, ibp, hb4, offb1, db1, sb1, pb2, cvec2);
  k_gemm_emb<<<dim3(DD/128, (BB*TOK)/128, 1), 256, 0, stream>>>(feat, wtokT, ctx_bf, ctxT_bf, btok, pos_emb);
  k_gather2<<<BKQ, 256, 0, stream>>>(ctx_bf, t_idx, x);

  for (int l = 0; l < LL; l++){
    // AT = scale * Wq·Wk^T and WVO = Wv·Wo (per-head) in one dispatch
    k_wqkvo<<<2048, 256, 0, stream>>>(Wq + (size_t)l*DD*DD, Wk + (size_t)l*DD*DD,
                                      Wv + (size_t)l*DD*DD, Wo + (size_t)l*DD*DD, ATb, WVOb);
    // z = LN1(x) @ AT^T  (z layout [b][q*16+h][dout])
    k_mf64<0,0,0,1,0,0,1><<<dim3(128,1), 256, 0, stream>>>(
        nullptr, x, g1 + l*DD, b1n + l*DD, ATb, nullptr,
        nullptr, z_bf, nullptr, 8192, DD, DD, DD, 1.f);
    // logits[b] = Z_b (256x512) @ ctx_b^T -> bf16
    k_gemm_bt64<1><<<dim3(TOK/64, 2, BB), 256, 0, stream>>>(
        z_bf, ctx_bf, nullptr, logits,
        DD, DD, DD, TOK, (long)QH*DD, (long)TOK*DD, (long)QH*TOK, 1);
    k_softmax<<<BB*QH, 256, 0, stream>>>(logits, att_bf);
    // parts[b*8+ks] = att_b @ ctxT_b^T over K-slice ks (bf16 partials)
    k_gemm_bt64<2><<<dim3(DD/64, 2, BB*8), 256, 0, stream>>>(
        att_bf, ctxT_bf, nullptr, parts,
        TOK/8, TOK, TOK, DD, (long)QH*TOK, (long)DD*TOK, (long)QH*DD, 8);
    k_red8<<<512, 256, 0, stream>>>(parts, c_flat);
    // x += c_flat @ WVO^T   (K=8192, ksplit=16, atomic)
    k_mf64<0,1,0,0,0,0,0><<<dim3(8,16), 256, 0, stream>>>(
        c_flat, nullptr, nullptr, nullptr, WVOb, nullptr,
        x, nullptr, nullptr, DD, 8192, 512, DD, 1.f);
    // mid = gelu(LN2(x) @ W1 + bf1)  -> bf16
    k_mf64<2,0,1,1,0,0,0><<<dim3(MM/64,1), 256, 0, stream>>>(
        nullptr, x, g2 + l*DD, b2n + l*DD, w1T + (size_t)l*DD*MM, bf1 + l*MM,
        nullptr, mid_bf, nullptr, MM, DD, DD, MM, 1.f);
    // x += mid @ W2 + bf2  (ksplit=8, atomic)
    k_mf64<0,1,0,0,0,0,0><<<dim3(8,8), 256, 0, stream>>>(
        mid_bf, nullptr, nullptr, nullptr, w2T + (size_t)l*MM*DD, bf2 + l*DD,
        x, nullptr, nullptr, DD, MM, MM/8, DD, 1.f);
  }

  // heads: h4 = relu(x @ [offW1|dW1|sW1|pW1] + hb4), bf16 copy of pose slice (x converted in-block)
  k_mf64<1,0,0,2,0,1,0><<<dim3(32,1), 256, 0, stream>>>(
      nullptr, x, nullptr, nullptr, headsT, hb4,
      h4, nullptr, hp_bf, 2048, DD, DD, 2048, 1.f);
  // rot6d = h_p @ pW2 + (pb2 + ibp)
  k_mf64<0,0,0,0,1,0,0><<<dim3(16,1), 256, 0, stream>>>(
      hp_bf, nullptr, nullptr, nullptr, pw2T, cvec2,
      rot6d, nullptr, nullptr, NROT, DD, DD, NROT, 1.f);
  k_final<<<BKQ, 256, 0, stream>>>(h4, rot6d, offW2, offb2, dW2, db2, sW2, sb2,
                                   K_cam, useful, t_mask, t_col, t_row, out);
}

// Round 13
// 879.822 us; speedup vs baseline: 1.1266x; 1.0219x over previous
//
#include <hip/hip_runtime.h>

typedef unsigned int uint;
typedef unsigned short u16;

#define BB 4
#define CE 384
#define DD 512
#define LL 8
#define HH 16
#define MM 2048
#define NJ 163
#define TOK 4096
#define BKQ 64
#define QH 256
#define OUTW 1486
#define NROT 978
#define QKSCALE 0.17677669529663687f

typedef __attribute__((ext_vector_type(8))) short short8;
typedef __attribute__((ext_vector_type(4))) float float4v;

static __device__ __forceinline__ u16 f2bf(float f){
  union { float f; uint u; } c; c.f = f;
  uint u = c.u;
  return (u16)((u + 0x7FFFu + ((u >> 16) & 1u)) >> 16);
}
static __device__ __forceinline__ float bf2f(u16 u){
  union { uint u; float f; } c; c.u = ((uint)u) << 16;
  return c.f;
}
static __device__ __forceinline__ float wred_sum(float v){
  for (int o = 32; o; o >>= 1) v += __shfl_xor(v, o, 64);
  return v;
}
static __device__ __forceinline__ void gl16(const void* g, void* l){
  __builtin_amdgcn_global_load_lds((const __attribute__((address_space(1))) void*)g,
                                   (__attribute__((address_space(3))) void*)l, 16, 0, 0);
}

// ---------------- unified prep: special blocks (NMS/pose/bias) decoupled from transpose blocks ----------------
struct PJobs {
  const float* s[24]; u16* d[24];
  int R[24], C[24], t0[25];
  int njobs, ntiles;
};
#define PREP_SPECIAL 132
__global__ __launch_bounds__(256) void k_prep_all(PJobs J,
    const float* __restrict__ scores,
    int* __restrict__ oidx, float* __restrict__ omask, float* __restrict__ ocol, float* __restrict__ orow,
    const float* __restrict__ pW1, const float* __restrict__ pb1,
    const float* __restrict__ ibp, float* __restrict__ hb4,
    const float* __restrict__ offb1, const float* __restrict__ db1, const float* __restrict__ sb1,
    const float* __restrict__ pb2, float* __restrict__ cvec2)
{
  int bid = blockIdx.x, t = threadIdx.x;
  __shared__ float sraw[4096];
  __shared__ float sv[4]; __shared__ int si[4]; __shared__ int swin;
  __shared__ u16 tb[32][66];

  if (bid < 4){
    // ---- NMS + top-k (exact fp32, stable ties), one batch per block ----
    int b = bid;
    const float* sp = scores + (size_t)b * 4096;
    for (int i = t; i < 4096; i += 256) sraw[i] = sp[i];
    __syncthreads();
    float v[16];
    #pragma unroll
    for (int j = 0; j < 16; j++){
      int i = t + j*256;
      int r = i >> 6, c = i & 63;
      float mx = -1e30f;
      for (int dr = -1; dr <= 1; dr++){
        int rr = r + dr; if (rr < 0 || rr > 63) continue;
        for (int dc = -1; dc <= 1; dc++){
          int cc = c + dc; if (cc < 0 || cc > 63) continue;
          mx = fmaxf(mx, sraw[rr*64+cc]);
        }
      }
      float s = sraw[i];
      v[j] = (s == mx) ? s : 0.0f;
    }
    int lane = t & 63, wv = t >> 6;
    for (int iter = 0; iter < 16; iter++){
      float best = -1e30f; int bi_ = 1 << 30;
      #pragma unroll
      for (int j = 0; j < 16; j++){
        if (v[j] > best){ best = v[j]; bi_ = t + j*256; }
      }
      #pragma unroll
      for (int o = 32; o; o >>= 1){
        float ov = __shfl_xor(best, o, 64);
        int oi = __shfl_xor(bi_, o, 64);
        if (ov > best || (ov == best && oi < bi_)){ best = ov; bi_ = oi; }
      }
      if (lane == 0){ sv[wv] = best; si[wv] = bi_; }
      __syncthreads();
      if (t == 0){
        float bb = sv[0]; int ii = si[0];
        for (int k = 1; k < 4; k++){
          if (sv[k] > bb || (sv[k] == bb && si[k] < ii)){ bb = sv[k]; ii = si[k]; }
        }
        oidx[b*16+iter] = ii;
        omask[b*16+iter] = (bb >= 0.3f) ? 1.f : 0.f;
        ocol[b*16+iter] = (float)(ii & 63);
        orow[b*16+iter] = (float)(ii >> 6);
        swin = ii;
      }
      __syncthreads();
      int wi = swin;
      if ((wi & 255) == t) v[wi >> 8] = -1e30f;
      __syncthreads();
    }
    return;
  } else if (bid < 132){
    int d = (bid - 4)*4 + (t >> 6);
    int ln = t & 63;
    float acc = 0.f;
    for (int i = ln; i < NJ*6; i += 64) acc += ibp[i] * pW1[(size_t)(DD+i)*DD + d];
    acc = wred_sum(acc);
    if (ln == 0) hb4[1536 + d] = acc + pb1[d];
    if (bid == 4){
      for (int i = t; i < 1536; i += 256)
        hb4[i] = (i < 512) ? offb1[i] : (i < 1024 ? db1[i-512] : sb1[i-1024]);
      for (int i = t; i < 1024; i += 256)
        cvec2[i] = (i < NJ*6) ? (pb2[i] + ibp[i]) : 0.f;
    }
    return;
  }

  // ---- transpose tiles only (blocks 132+): 64(r) x 32(c), bf16 LDS, packed-uint writes ----
  for (int g = bid - PREP_SPECIAL; g < J.ntiles; g += (gridDim.x - PREP_SPECIAL)){
    int j = 0;
    while (g >= J.t0[j+1]) j++;
    int ti = g - J.t0[j];
    int C_ = J.C[j], R_ = J.R[j];
    int tC = (C_ + 31) >> 5;
    int ry = ti / tC, cx = ti - ry*tC;
    int r0 = ry*64, c0 = cx*32;
    int tx = t & 31, ty = t >> 5;
    const float* src = J.s[j]; u16* dst = J.d[j];
    __syncthreads();
    #pragma unroll
    for (int i = 0; i < 8; i++){
      int r = ty + i*8;
      float v = 0.f;
      if (c0+tx < C_) v = src[(size_t)(r0+r)*C_ + c0+tx];
      tb[tx][r] = f2bf(v);
    }
    __syncthreads();
    #pragma unroll
    for (int p = 0; p < 4; p++){
      int c = (t >> 5) + p*8;
      int rr = t & 31;
      if (c0 + c < C_){
        uint val = (uint)tb[c][2*rr] | ((uint)tb[c][2*rr+1] << 16);
        *(uint*)&dst[(size_t)(c0+c)*R_ + r0 + rr*2] = val;
      }
    }
  }
}

// ---------------- AT/WVO prep, per layer (2048 blocks) ----------------
__global__ __launch_bounds__(256) void k_wqkvo(const float* __restrict__ wq, const float* __restrict__ wk,
    const float* __restrict__ wv, const float* __restrict__ wo,
    u16* __restrict__ AT, u16* __restrict__ WVOT)
{
  __shared__ __align__(16) u16 As[2560];
  __shared__ __align__(16) u16 Bs[2560];
  int t = threadIdx.x;
  int lane = t & 63, w = t >> 6, lr = lane & 15, lk = lane >> 4;
  float4v acc[4];
  float4v z4 = {0.f,0.f,0.f,0.f};
  acc[0]=z4; acc[1]=z4; acc[2]=z4; acc[3]=z4;
  if (blockIdx.x < 1024){
    int id = blockIdx.x;
    int rt = id & 127, dt = id >> 7;
    int h = rt >> 3, dout0 = (rt & 7)*64, din0 = dt*64;
    int r = t >> 2, c0 = (t & 3)*8;
    {
      float4 u0 = *(const float4*)(wk + (size_t)(dout0+r)*DD + h*32 + c0);
      float4 u1 = *(const float4*)(wk + (size_t)(dout0+r)*DD + h*32 + c0 + 4);
      u16* d = As + r*40 + c0;
      d[0]=f2bf(u0.x); d[1]=f2bf(u0.y); d[2]=f2bf(u0.z); d[3]=f2bf(u0.w);
      d[4]=f2bf(u1.x); d[5]=f2bf(u1.y); d[6]=f2bf(u1.z); d[7]=f2bf(u1.w);
      float4 v0 = *(const float4*)(wq + (size_t)(din0+r)*DD + h*32 + c0);
      float4 v1 = *(const float4*)(wq + (size_t)(din0+r)*DD + h*32 + c0 + 4);
      u16* e = Bs + r*40 + c0;
      e[0]=f2bf(v0.x); e[1]=f2bf(v0.y); e[2]=f2bf(v0.z); e[3]=f2bf(v0.w);
      e[4]=f2bf(v1.x); e[5]=f2bf(v1.y); e[6]=f2bf(v1.z); e[7]=f2bf(v1.w);
    }
    __syncthreads();
    short8 af = *(const short8*)&As[(w*16+lr)*40 + lk*8];
    #pragma unroll
    for (int nf = 0; nf < 4; nf++){
      short8 bf8 = *(const short8*)&Bs[(nf*16+lr)*40 + lk*8];
      acc[nf] = __builtin_amdgcn_mfma_f32_16x16x32_bf16(af, bf8, acc[nf], 0, 0, 0);
    }
    #pragma unroll
    for (int nf = 0; nf < 4; nf++){
      #pragma unroll
      for (int jj = 0; jj < 4; jj++){
        int row = w*16 + lk*4 + jj;
        AT[(size_t)(h*512 + dout0 + row)*DD + din0 + nf*16 + lr] = f2bf(acc[nf][jj]*QKSCALE);
      }
    }
  } else {
    int id = blockIdx.x - 1024;
    int ct = id & 127, dt = id >> 7;
    int h = ct >> 3, Dc0 = (ct & 7)*64, dout0 = dt*64;
    {
      int c = t >> 3, d8 = (t & 7)*8;
      float4 a0 = *(const float4*)(wo + (size_t)(h*32+c)*DD + dout0 + d8);
      float4 a1 = *(const float4*)(wo + (size_t)(h*32+c)*DD + dout0 + d8 + 4);
      As[(d8+0)*40 + c] = f2bf(a0.x);
      As[(d8+1)*40 + c] = f2bf(a0.y);
      As[(d8+2)*40 + c] = f2bf(a0.z);
      As[(d8+3)*40 + c] = f2bf(a0.w);
      As[(d8+4)*40 + c] = f2bf(a1.x);
      As[(d8+5)*40 + c] = f2bf(a1.y);
      As[(d8+6)*40 + c] = f2bf(a1.z);
      As[(d8+7)*40 + c] = f2bf(a1.w);
      int r = t >> 2, c0 = (t & 3)*8;
      float4 v0 = *(const float4*)(wv + (size_t)(Dc0+r)*DD + h*32 + c0);
      float4 v1 = *(const float4*)(wv + (size_t)(Dc0+r)*DD + h*32 + c0 + 4);
      u16* e = Bs + r*40 + c0;
      e[0]=f2bf(v0.x); e[1]=f2bf(v0.y); e[2]=f2bf(v0.z); e[3]=f2bf(v0.w);
      e[4]=f2bf(v1.x); e[5]=f2bf(v1.y); e[6]=f2bf(v1.z); e[7]=f2bf(v1.w);
    }
    __syncthreads();
    short8 af = *(const short8*)&As[(w*16+lr)*40 + lk*8];
    #pragma unroll
    for (int nf = 0; nf < 4; nf++){
      short8 bf8 = *(const short8*)&Bs[(nf*16+lr)*40 + lk*8];
      acc[nf] = __builtin_amdgcn_mfma_f32_16x16x32_bf16(af, bf8, acc[nf], 0, 0, 0);
    }
    #pragma unroll
    for (int nf = 0; nf < 4; nf++){
      #pragma unroll
      for (int jj = 0; jj < 4; jj++){
        int row = w*16 + lk*4 + jj;
        WVOT[(size_t)(dout0 + row)*8192 + h*512 + Dc0 + nf*16 + lr] = f2bf(acc[nf][jj]);
      }
    }
  }
}

// ---------------- reduce 8 PV split-K bf16 partials -> c_flat bf16 [bq][h*512+Dc] ----------------
__global__ __launch_bounds__(256) void k_red8(const u16* __restrict__ parts, u16* __restrict__ cf){
  int i4 = blockIdx.x*256 + threadIdx.x;
  int elem = i4*4;
  int row = elem >> 13, col = elem & 8191;
  int b = row >> 4, q = row & 15, h = col >> 9, Dc = col & 511;
  const u16* src = parts + ((size_t)b*8)*131072 + (size_t)(q*16+h)*512 + Dc;
  float s0 = 0.f, s1 = 0.f, s2 = 0.f, s3 = 0.f;
  #pragma unroll
  for (int ks = 0; ks < 8; ks++){
    ushort4 g = *(const ushort4*)(src + (size_t)ks*131072);
    s0 += bf2f(g.x); s1 += bf2f(g.y); s2 += bf2f(g.z); s3 += bf2f(g.w);
  }
  ushort4 o;
  o.x = f2bf(s0); o.y = f2bf(s1); o.z = f2bf(s2); o.w = f2bf(s3);
  *(ushort4*)&cf[(size_t)row*8192 + col] = o;
}

// ---------------- ctx embed GEMM: ctx = feat(fp32) @ wtokT^T + btok + pos_emb -> bf16 ctx + ctxT ----------------
__global__ __launch_bounds__(256) void k_gemm_emb(
    const float* __restrict__ feat, const u16* __restrict__ Bt,
    u16* __restrict__ ctx, u16* __restrict__ ctxT,
    const float* __restrict__ ep1, const float* __restrict__ ep2)
{
  __shared__ __align__(16) u16 SM[16640];
  u16* As = SM;
  u16* Bs = SM + 8192;
  int m0 = blockIdx.y*128, n0 = blockIdx.x*128;
  int t = threadIdx.x, lane = t & 63, wave = t >> 6;
  int wr = wave >> 1, wc = wave & 1;
  int lr = lane & 15, lk = lane >> 4;
  int sr8 = t >> 3, sl = t & 7;
  int sw = ((sl ^ (sr8 & 7)) * 8);
  float4v acc[4][4];
  float4v z4 = {0.f, 0.f, 0.f, 0.f};
  #pragma unroll
  for (int i = 0; i < 4; i++)
    #pragma unroll
    for (int j = 0; j < 4; j++) acc[i][j] = z4;
  for (int kt = 0; kt < CE; kt += 64){
    __syncthreads();
    #pragma unroll
    for (int p = 0; p < 8; p++){
      int r = (t >> 4) + p*16, f4 = t & 15;
      float4 v = *(const float4*)&feat[(size_t)(m0+r)*CE + kt + f4*4];
      int dc = ((f4 >> 1) ^ (r & 7))*8 + (f4 & 1)*4;
      ushort4 o; o.x = f2bf(v.x); o.y = f2bf(v.y); o.z = f2bf(v.z); o.w = f2bf(v.w);
      *(ushort4*)&As[r*64 + dc] = o;
    }
    #pragma unroll
    for (int rg = 0; rg < 4; rg++)
      gl16(Bt + (size_t)(n0 + rg*32 + sr8)*CE + kt + sw, Bs + rg*2048 + 8*t);
    __syncthreads();
    #pragma unroll
    for (int s = 0; s < 2; s++){
      int slot = ((s*4 + lk) ^ (lr & 7)) * 8;
      short8 af[4], bfr[4];
      #pragma unroll
      for (int i = 0; i < 4; i++) af[i] = *(const short8*)&As[(wr*64 + i*16 + lr)*64 + slot];
      #pragma unroll
      for (int j = 0; j < 4; j++) bfr[j] = *(const short8*)&Bs[(wc*64 + j*16 + lr)*64 + slot];
      #pragma unroll
      for (int i = 0; i < 4; i++)
        #pragma unroll
        for (int j = 0; j < 4; j++)
          acc[i][j] = __builtin_amdgcn_mfma_f32_16x16x32_bf16(af[i], bfr[j], acc[i][j], 0, 0, 0);
    }
  }
  __syncthreads();
  #pragma unroll
  for (int i = 0; i < 4; i++){
    int rbase = m0 + wr*64 + i*16 + lk*4;
    #pragma unroll
    for (int j = 0; j < 4; j++){
      int cc = n0 + wc*64 + j*16 + lr;
      #pragma unroll
      for (int jj = 0; jj < 4; jj++){
        int rr = rbase + jj;
        float vv = acc[i][j][jj] + ep1[cc] + ep2[(size_t)(rr & 4095)*DD + cc];
        u16 bv = f2bf(vv);
        ctx[(size_t)rr*DD + cc] = bv;
        SM[(cc - n0)*130 + (rr - m0)] = bv;
      }
    }
  }
  __syncthreads();
  int b = m0 >> 12, tok0 = m0 & 4095;
  int tx = t & 63, ty = t >> 6;
  #pragma unroll 4
  for (int it = 0; it < 32; it++){
    int c = ty*32 + it;
    uint vv = *(const uint*)&SM[c*130 + tx*2];
    *(uint*)&ctxT[((size_t)b*DD + n0 + c)*TOK + tok0 + tx*2] = vv;
  }
}

// ---------------- gather x0 from ctx rows (bf16 -> fp32) ----------------
__global__ __launch_bounds__(256) void k_gather2(const u16* __restrict__ ctx, const int* __restrict__ oidx,
    float* __restrict__ x)
{
  int bq = blockIdx.x, t = threadIdx.x;
  int b = bq >> 4, tok = oidx[bq];
  uint v = ((const uint*)(ctx + ((size_t)b*TOK + tok)*DD))[t];
  float2 o; o.x = bf2f((u16)(v & 0xFFFF)); o.y = bf2f((u16)(v >> 16));
  *(float2*)&x[(size_t)bq*DD + t*2] = o;
}

// ---------------- MFMA GEMM, 128(M) x 64(N) tiles: C = A(MxK) @ Bt(NxK)^T ----------------
// EPI 1: bf16 store batch slice.  EPI 2: bf16 store slice bz (split-K partials).
template<int EPI>
__global__ __launch_bounds__(256) void k_gemm_bt64(
    const u16* __restrict__ A, const u16* __restrict__ Bt,
    float* __restrict__ C, u16* __restrict__ Cb,
    int Kslice, int lda, int ldb, int ldc,
    long sA, long sB, long sC, int ksplit)
{
  int bz = blockIdx.z;
  int batch = bz / ksplit, ks = bz - batch*ksplit;
  const u16* Ab = A + (size_t)batch*sA + (size_t)ks*Kslice;
  const u16* Bb = Bt + (size_t)batch*sB + (size_t)ks*Kslice;
  int m0 = blockIdx.y*128, n0 = blockIdx.x*64;
  __shared__ __align__(16) u16 As[128*64];
  __shared__ __align__(16) u16 Bs[64*64];
  int t = threadIdx.x, lane = t & 63, w = t >> 6;
  int lr = lane & 15, lk = lane >> 4;
  int sr8 = t >> 3, sl = t & 7;
  int sw = ((sl ^ (sr8 & 7)) * 8);
  float4v acc[2][4];
  float4v z4 = {0.f,0.f,0.f,0.f};
  #pragma unroll
  for (int i = 0; i < 2; i++)
    #pragma unroll
    for (int j = 0; j < 4; j++) acc[i][j] = z4;

  for (int kt = 0; kt < Kslice; kt += 64){
    __syncthreads();
    #pragma unroll
    for (int rg = 0; rg < 4; rg++)
      gl16(Ab + (size_t)(m0 + rg*32 + sr8)*lda + kt + sw, As + rg*2048 + 8*t);
    #pragma unroll
    for (int rg = 0; rg < 2; rg++)
      gl16(Bb + (size_t)(n0 + rg*32 + sr8)*ldb + kt + sw, Bs + rg*2048 + 8*t);
    __syncthreads();
    #pragma unroll
    for (int s = 0; s < 2; s++){
      int slot = ((s*4 + lk) ^ (lr & 7)) * 8;
      short8 af[2], bfr[4];
      #pragma unroll
      for (int i = 0; i < 2; i++) af[i] = *(const short8*)&As[(w*32 + i*16 + lr)*64 + slot];
      #pragma unroll
      for (int j = 0; j < 4; j++) bfr[j] = *(const short8*)&Bs[(j*16 + lr)*64 + slot];
      #pragma unroll
      for (int i = 0; i < 2; i++)
        #pragma unroll
        for (int j = 0; j < 4; j++)
          acc[i][j] = __builtin_amdgcn_mfma_f32_16x16x32_bf16(af[i], bfr[j], acc[i][j], 0, 0, 0);
    }
  }
  #pragma unroll
  for (int i = 0; i < 2; i++){
    int rbase = m0 + w*32 + i*16 + lk*4;
    #pragma unroll
    for (int j = 0; j < 4; j++){
      int cc = n0 + j*16 + lr;
      #pragma unroll
      for (int jj = 0; jj < 4; jj++){
        int rr = rbase + jj;
        if (EPI == 1) Cb[(size_t)batch*sC + (size_t)rr*ldc + cc] = f2bf(acc[i][j][jj]);
        else Cb[(size_t)bz*sC + (size_t)rr*ldc + cc] = f2bf(acc[i][j][jj]);
      }
    }
  }
}

// ---------------- skinny MFMA GEMM: C(64 x N) = A(64 x K) @ Bt(N x K)^T ----------------
// ACT: 0 none, 1 relu, 2 gelu.  RES: 0 store, 1 atomicAdd.  OUTB: bf16 out.
// DOLN: 0 gl16 A, 1 LN(xf) in-block, 2 convert xf in-block.  NG: guard col<N.
// HPB: bf16 copy of cols>=1536.  ZMAP: z-layout store.
template<int ACT, int RES, int OUTB, int DOLN, int NG, int HPB, int ZMAP = 0>
__global__ __launch_bounds__(256) void k_mf64(
    const u16* __restrict__ A, const float* __restrict__ xf,
    const float* __restrict__ g, const float* __restrict__ bb,
    const u16* __restrict__ Bt, const float* __restrict__ bias,
    float* __restrict__ C, u16* __restrict__ Cb, u16* __restrict__ Cb2,
    int N, int K, int kper, int ldc, float alpha)
{
  __shared__ __align__(16) u16 Asl[DOLN ? 64*520 : 64*64];
  __shared__ __align__(16) u16 Bs[64*64];
  int t = threadIdx.x, lane = t & 63, w = t >> 6;
  int lr = lane & 15, lk = lane >> 4;
  int n0 = blockIdx.x*64;
  int ks = blockIdx.y, kbeg = ks*kper;
  int sr8 = t >> 3, sl = t & 7;
  int sw = ((sl ^ (sr8 & 7)) * 8);

  if (DOLN == 1){
    for (int rr = 0; rr < 16; rr++){
      int row = w*16 + rr;
      const float* xr = xf + (size_t)row*DD;
      float4 v0 = *(const float4*)(xr + lane*4);
      float4 v1 = *(const float4*)(xr + 256 + lane*4);
      float s = v0.x+v0.y+v0.z+v0.w + v1.x+v1.y+v1.z+v1.w;
      s = wred_sum(s);
      float mu = s * (1.f/DD);
      float d0=v0.x-mu, d1=v0.y-mu, d2=v0.z-mu, d3=v0.w-mu;
      float e0=v1.x-mu, e1=v1.y-mu, e2=v1.z-mu, e3=v1.w-mu;
      float q = d0*d0+d1*d1+d2*d2+d3*d3 + e0*e0+e1*e1+e2*e2+e3*e3;
      q = wred_sum(q);
      float inv = rsqrtf(q * (1.f/DD) + 1e-5f);
      float4 g0 = *(const float4*)(g + lane*4);
      float4 g1 = *(const float4*)(g + 256 + lane*4);
      float4 b0 = *(const float4*)(bb + lane*4);
      float4 b1 = *(const float4*)(bb + 256 + lane*4);
      u16* dst = &Asl[row*520];
      dst[lane*4+0] = f2bf(d0*inv*g0.x + b0.x);
      dst[lane*4+1] = f2bf(d1*inv*g0.y + b0.y);
      dst[lane*4+2] = f2bf(d2*inv*g0.z + b0.z);
      dst[lane*4+3] = f2bf(d3*inv*g0.w + b0.w);
      dst[256+lane*4+0] = f2bf(e0*inv*g1.x + b1.x);
      dst[256+lane*4+1] = f2bf(e1*inv*g1.y + b1.y);
      dst[256+lane*4+2] = f2bf(e2*inv*g1.z + b1.z);
      dst[256+lane*4+3] = f2bf(e3*inv*g1.w + b1.w);
    }
  } else if (DOLN == 2){
    for (int rr = 0; rr < 16; rr++){
      int row = w*16 + rr;
      const float* xr = xf + (size_t)row*DD;
      float4 v0 = *(const float4*)(xr + lane*4);
      float4 v1 = *(const float4*)(xr + 256 + lane*4);
      u16* dst = &Asl[row*520];
      dst[lane*4+0] = f2bf(v0.x);
      dst[lane*4+1] = f2bf(v0.y);
      dst[lane*4+2] = f2bf(v0.z);
      dst[lane*4+3] = f2bf(v0.w);
      dst[256+lane*4+0] = f2bf(v1.x);
      dst[256+lane*4+1] = f2bf(v1.y);
      dst[256+lane*4+2] = f2bf(v1.z);
      dst[256+lane*4+3] = f2bf(v1.w);
    }
  }

  float4v acc[4];
  float4v z4 = {0.f,0.f,0.f,0.f};
  acc[0]=z4; acc[1]=z4; acc[2]=z4; acc[3]=z4;

  for (int kc = kbeg; kc < kbeg + kper; kc += 64){
    __syncthreads();
    if (!DOLN){
      gl16(A + (size_t)sr8*K + kc + sw,        (u16*)Asl + 8*t);
      gl16(A + (size_t)(32+sr8)*K + kc + sw,   (u16*)Asl + 2048 + 8*t);
    }
    gl16(Bt + (size_t)(n0+sr8)*K + kc + sw,      (u16*)Bs + 8*t);
    gl16(Bt + (size_t)(n0+32+sr8)*K + kc + sw,   (u16*)Bs + 2048 + 8*t);
    __syncthreads();
    #pragma unroll
    for (int s = 0; s < 2; s++){
      int slot = ((s*4 + lk) ^ (lr & 7)) * 8;
      short8 af;
      if (DOLN) af = *(const short8*)&Asl[(w*16+lr)*520 + kc + s*32 + lk*8];
      else      af = *(const short8*)&Asl[(w*16+lr)*64 + slot];
      #pragma unroll
      for (int nf = 0; nf < 4; nf++){
        short8 bf8 = *(const short8*)&Bs[(nf*16+lr)*64 + slot];
        acc[nf] = __builtin_amdgcn_mfma_f32_16x16x32_bf16(af, bf8, acc[nf], 0, 0, 0);
      }
    }
  }
  #pragma unroll
  for (int nf = 0; nf < 4; nf++){
    int col = n0 + nf*16 + lr;
    float bsv = (bias && ks == 0) ? bias[col] : 0.f;
    #pragma unroll
    for (int jj = 0; jj < 4; jj++){
      int row = w*16 + lk*4 + jj;
      float v = acc[nf][jj]*alpha + bsv;
      if (ACT == 1) v = fmaxf(v, 0.f);
      else if (ACT == 2) v = 0.5f*v*(1.f + tanhf(0.7978845608028654f*(v + 0.044715f*v*v*v)));
      if (NG && col >= N) continue;
      if (ZMAP){
        int b_ = row >> 4, q_ = row & 15, h_ = col >> 9, d_ = col & 511;
        Cb[((size_t)b_*QH + (q_ << 4) + h_)*DD + d_] = f2bf(v);
        continue;
      }
      size_t o = (size_t)row*ldc + col;
      if (OUTB == 1) Cb[o] = f2bf(v);
      else if (RES == 0) C[o] = v;
      else atomicAdd(&C[o], v);
      if (HPB && col >= 1536) Cb2[(size_t)row*DD + (col - 1536)] = f2bf(v);
    }
  }
}

// ---------------- softmax over 4096, bf16 in -> bf16 probs (packed uint IO) ----------------
__global__ __launch_bounds__(256) void k_softmax(const u16* __restrict__ lg, u16* __restrict__ att){
  int row = blockIdx.x, t = threadIdx.x;
  const uint* p = (const uint*)(lg + (size_t)row*TOK);
  uint pv[8]; float v0[8], v1[8]; float mx = -1e30f;
  #pragma unroll
  for (int i = 0; i < 8; i++){
    pv[i] = p[t + i*256];
    v0[i] = bf2f((u16)(pv[i] & 0xFFFF));
    v1[i] = bf2f((u16)(pv[i] >> 16));
    mx = fmaxf(mx, fmaxf(v0[i], v1[i]));
  }
  int lane = t & 63, w = t >> 6;
  for (int o = 32; o; o >>= 1) mx = fmaxf(mx, __shfl_xor(mx, o, 64));
  __shared__ float sm[4]; __shared__ float ssum[4];
  if (lane == 0) sm[w] = mx;
  __syncthreads();
  mx = fmaxf(fmaxf(sm[0], sm[1]), fmaxf(sm[2], sm[3]));
  float s = 0.f;
  #pragma unroll
  for (int i = 0; i < 8; i++){
    v0[i] = expf(v0[i] - mx); v1[i] = expf(v1[i] - mx);
    s += v0[i] + v1[i];
  }
  s = wred_sum(s);
  if (lane == 0) ssum[w] = s;
  __syncthreads();
  s = ssum[0]+ssum[1]+ssum[2]+ssum[3];
  float inv = 1.f / s;
  uint* q = (uint*)(att + (size_t)row*TOK);
  #pragma unroll
  for (int i = 0; i < 8; i++){
    uint lo = f2bf(v0[i]*inv);
    uint hi = f2bf(v1[i]*inv);
    q[t + i*256] = lo | (hi << 16);
  }
}

// ---------------- final heads + Gram-Schmidt + assembly ----------------
__global__ __launch_bounds__(256) void k_final(
    const float* __restrict__ h4, const float* __restrict__ rot6d,
    const float* __restrict__ offW2, const float* __restrict__ offb2,
    const float* __restrict__ dW2, const float* __restrict__ db2,
    const float* __restrict__ sW2, const float* __restrict__ sb2,
    const float* __restrict__ K_cam, const float* __restrict__ useful,
    const float* __restrict__ maskf, const float* __restrict__ colf, const float* __restrict__ rowf,
    float* __restrict__ out)
{
  int bq = blockIdx.x, t = threadIdx.x, b = bq >> 4;
  float po0 = 0.f, po1 = 0.f, pd = 0.f, ps[11];
  #pragma unroll
  for (int j = 0; j < 11; j++) ps[j] = 0.f;
  const float* hrow = h4 + (size_t)bq*2048;
  for (int i = t; i < DD; i += 256){
    float ho = hrow[i];
    float hd = hrow[512 + i];
    float hs = hrow[1024 + i];
    po0 += ho*offW2[i*2]; po1 += ho*offW2[i*2+1];
    pd += hd*dW2[i];
    #pragma unroll
    for (int j = 0; j < 11; j++) ps[j] += hs*sW2[i*11+j];
  }
  __shared__ float sred[4][14];
  __shared__ float sout[14];
  int wv = t >> 6, ln = t & 63;
  float vals[14];
  vals[0] = po0; vals[1] = po1; vals[2] = pd;
  #pragma unroll
  for (int j = 0; j < 11; j++) vals[3+j] = ps[j];
  #pragma unroll
  for (int kk = 0; kk < 14; kk++){
    float r = wred_sum(vals[kk]);
    if (ln == 0) sred[wv][kk] = r;
  }
  __syncthreads();
  if (t < 14) sout[t] = sred[0][t]+sred[1][t]+sred[2][t]+sred[3][t];
  __syncthreads();
  float m = maskf[bq];
  if (t == 0){
    float off0 = sout[0] + offb2[0], off1 = sout[1] + offb2[1];
    float draw = sout[2] + db2[0];
    float l0 = (colf[bq] + 0.5f + off0) * 14.0f;
    float l1 = (rowf[bq] + 0.5f + off1) * 14.0f;
    float fx = K_cam[b*9+0], cx = K_cam[b*9+2], fy = K_cam[b*9+4], cy = K_cam[b*9+5];
    float dist = fx / fmaxf(expf(draw), 1e-5f);
    float tx = (l0 - cx) / fx * dist, ty = (l1 - cy) / fy * dist;
    float* o = out + (size_t)bq*OUTW;
    o[0] = l0*m; o[1] = l1*m; o[2] = off0*m; o[3] = off1*m; o[4] = dist*m;
    o[5] = tx*m; o[6] = ty*m; o[7] = dist*m;
    #pragma unroll
    for (int j = 0; j < 11; j++){ float sp = sout[3+j] + sb2[j]; o[8+j] = m / (1.f + expf(-sp)); }
  }
  if (t < NJ){
    const float* rp = rot6d + (size_t)bq*NROT + t*6;
    float a0 = rp[0], b0 = rp[1], a1 = rp[2], b1 = rp[3], a2 = rp[4], b2 = rp[5];
    float n0 = sqrtf(a0*a0 + a1*a1 + a2*a2);
    float i0 = 1.f / (n0 + 1e-8f);
    float u00 = a0*i0, u01 = a1*i0, u02 = a2*i0;
    float dt = b0*u00 + b1*u01 + b2*u02;
    float v0 = b0 - dt*u00, v1 = b1 - dt*u01, v2 = b2 - dt*u02;
    float n1 = sqrtf(v0*v0 + v1*v1 + v2*v2);
    float i1 = 1.f / (n1 + 1e-8f);
    float u10 = v0*i1, u11 = v1*i1, u12 = v2*i1;
    float u20 = u01*u12 - u02*u11;
    float u21 = u02*u10 - u00*u12;
    float u22 = u00*u11 - u01*u10;
    float um = useful[t], om = 1.f - um;
    float R00 = um*u00 + om, R01 = um*u10,      R02 = um*u20;
    float R10 = um*u01,      R11 = um*u11 + om, R12 = um*u21;
    float R20 = um*u02,      R21 = um*u12,      R22 = um*u22 + om;
    float* o = out + (size_t)bq*OUTW + 19 + t*9;
    o[0] = R00*m; o[1] = R01*m; o[2] = R02*m;
    o[3] = R10*m; o[4] = R11*m; o[5] = R12*m;
    o[6] = R20*m; o[7] = R21*m; o[8] = R22*m;
  }
}

extern "C" void kernel_launch(void* const* d_in, const int* in_sizes, int n_in,
                              void* d_out, int out_size, void* d_ws, size_t ws_size,
                              hipStream_t stream)
{
  const float* feat   = (const float*)d_in[0];
  const float* scores = (const float*)d_in[1];
  const float* K_cam  = (const float*)d_in[2];
  const float* pos_emb= (const float*)d_in[3];
  const float* Wtok   = (const float*)d_in[4];
  const float* btok   = (const float*)d_in[5];
  const float* Wq     = (const float*)d_in[6];
  const float* Wk     = (const float*)d_in[7];
  const float* Wv     = (const float*)d_in[8];
  const float* Wo     = (const float*)d_in[9];
  const float* g1     = (const float*)d_in[10];
  const float* b1n    = (const float*)d_in[11];
  const float* W1     = (const float*)d_in[12];
  const float* bf1    = (const float*)d_in[13];
  const float* W2     = (const float*)d_in[14];
  const float* bf2    = (const float*)d_in[15];
  const float* g2     = (const float*)d_in[16];
  const float* b2n    = (const float*)d_in[17];
  const float* offW1  = (const float*)d_in[18];
  const float* offb1  = (const float*)d_in[19];
  const float* offW2  = (const float*)d_in[20];
  const float* offb2  = (const float*)d_in[21];
  const float* dW1    = (const float*)d_in[22];
  const float* db1    = (const float*)d_in[23];
  const float* dW2    = (const float*)d_in[24];
  const float* db2    = (const float*)d_in[25];
  const float* sW1    = (const float*)d_in[26];
  const float* sb1    = (const float*)d_in[27];
  const float* sW2    = (const float*)d_in[28];
  const float* sb2    = (const float*)d_in[29];
  const float* pW1    = (const float*)d_in[30];
  const float* pb1    = (const float*)d_in[31];
  const float* pW2    = (const float*)d_in[32];
  const float* pb2    = (const float*)d_in[33];
  const float* ibp    = (const float*)d_in[34];
  const float* useful = (const float*)d_in[35];
  float* out = (float*)d_out;

  char* wsp = (char*)d_ws;
  size_t off = 0;
  auto alloc = [&](size_t bytes)->char*{
    char* p = wsp + off;
    off += (bytes + 255) & ~((size_t)255);
    return p;
  };
  int*   t_idx  = (int*)  alloc(BKQ*4);
  float* t_mask = (float*)alloc(BKQ*4);
  float* t_col  = (float*)alloc(BKQ*4);
  float* t_row  = (float*)alloc(BKQ*4);
  u16*   wtokT  = (u16*)  alloc((size_t)DD*CE*2);
  u16*   ctx_bf = (u16*)  alloc((size_t)BB*TOK*DD*2);
  u16*   ctxT_bf= (u16*)  alloc((size_t)BB*TOK*DD*2);
  u16*   ATb    = (u16*)  alloc((size_t)8192*DD*2);
  u16*   WVOb   = (u16*)  alloc((size_t)DD*8192*2);
  u16*   w1T    = (u16*)  alloc((size_t)LL*DD*MM*2);
  u16*   w2T    = (u16*)  alloc((size_t)LL*MM*DD*2);
  u16*   headsT = (u16*)  alloc((size_t)4*DD*DD*2);
  u16*   pw2T   = (u16*)  alloc((size_t)1024*DD*2);
  float* x      = (float*)alloc((size_t)BKQ*DD*4);
  u16*   z_bf   = (u16*)  alloc((size_t)BKQ*HH*DD*2);
  u16*   logits = (u16*)  alloc((size_t)BB*QH*TOK*2);
  u16*   att_bf = (u16*)  alloc((size_t)BB*QH*TOK*2);
  u16*   parts  = (u16*)  alloc((size_t)BB*8*QH*DD*2);
  u16*   c_flat = (u16*)  alloc((size_t)BKQ*8192*2);
  u16*   mid_bf = (u16*)  alloc((size_t)BKQ*MM*2);
  float* h4     = (float*)alloc((size_t)BKQ*2048*4);
  u16*   hp_bf  = (u16*)  alloc((size_t)BKQ*DD*2);
  float* hb4    = (float*)alloc(2048*4);
  float* cvec2  = (float*)alloc(1024*4);
  float* rot6d  = (float*)alloc((size_t)BKQ*NROT*4);
  if (off > ws_size) return;

  // job table for unified weight transposer (64x32 tiles; R multiple of 64)
  PJobs J;
  int ntl = 0, nj = 0;
  auto addjob = [&](const float* s, u16* d, int R, int C){
    J.s[nj] = s; J.d[nj] = d; J.R[nj] = R; J.C[nj] = C; J.t0[nj] = ntl;
    ntl += (R/64) * ((C+31)/32);
    nj++;
  };
  addjob(Wtok, wtokT, CE, DD);
  for (int l = 0; l < LL; l++) addjob(W1 + (size_t)l*DD*MM, w1T + (size_t)l*MM*DD, DD, MM);
  for (int l = 0; l < LL; l++) addjob(W2 + (size_t)l*MM*DD, w2T + (size_t)l*DD*MM, MM, DD);
  addjob(offW1, headsT,            DD, DD);
  addjob(dW1,   headsT + DD*DD,    DD, DD);
  addjob(sW1,   headsT + 2*DD*DD,  DD, DD);
  addjob(pW1,   headsT + 3*DD*DD,  DD, DD);
  addjob(pW2,   pw2T, DD, NROT);
  J.t0[nj] = ntl; J.njobs = nj; J.ntiles = ntl;

  k_prep_all<<<2048 + PREP_SPECIAL, 256, 0, stream>>>(J, scores, t_idx, t_mask, t_col, t_row,
                                       pW1, pb1, ibp, hb4, offb1, db1, sb1, pb2, cvec2);
  k_gemm_emb<<<dim3(DD/128, (BB*TOK)/128, 1), 256, 0, stream>>>(feat, wtokT, ctx_bf, ctxT_bf, btok, pos_emb);
  k_gather2<<<BKQ, 256, 0, stream>>>(ctx_bf, t_idx, x);

  for (int l = 0; l < LL; l++){
    // AT = scale * Wq·Wk^T and WVO = Wv·Wo (per-head) in one dispatch
    k_wqkvo<<<2048, 256, 0, stream>>>(Wq + (size_t)l*DD*DD, Wk + (size_t)l*DD*DD,
                                      Wv + (size_t)l*DD*DD, Wo + (size_t)l*DD*DD, ATb, WVOb);
    // z = LN1(x) @ AT^T  (z layout [b][q*16+h][dout])
    k_mf64<0,0,0,1,0,0,1><<<dim3(128,1), 256, 0, stream>>>(
        nullptr, x, g1 + l*DD, b1n + l*DD, ATb, nullptr,
        nullptr, z_bf, nullptr, 8192, DD, DD, DD, 1.f);
    // logits[b] = Z_b (256x512) @ ctx_b^T -> bf16
    k_gemm_bt64<1><<<dim3(TOK/64, 2, BB), 256, 0, stream>>>(
        z_bf, ctx_bf, nullptr, logits,
        DD, DD, DD, TOK, (long)QH*DD, (long)TOK*DD, (long)QH*TOK, 1);
    k_softmax<<<BB*QH, 256, 0, stream>>>(logits, att_bf);
    // parts[b*8+ks] = att_b @ ctxT_b^T over K-slice ks (bf16 partials)
    k_gemm_bt64<2><<<dim3(DD/64, 2, BB*8), 256, 0, stream>>>(
        att_bf, ctxT_bf, nullptr, parts,
        TOK/8, TOK, TOK, DD, (long)QH*TOK, (long)DD*TOK, (long)QH*DD, 8);
    k_red8<<<512, 256, 0, stream>>>(parts, c_flat);
    // x += c_flat @ WVO^T   (K=8192, ksplit=16, atomic)
    k_mf64<0,1,0,0,0,0,0><<<dim3(8,16), 256, 0, stream>>>(
        c_flat, nullptr, nullptr, nullptr, WVOb, nullptr,
        x, nullptr, nullptr, DD, 8192, 512, DD, 1.f);
    // mid = gelu(LN2(x) @ W1 + bf1)  -> bf16
    k_mf64<2,0,1,1,0,0,0><<<dim3(MM/64,1), 256, 0, stream>>>(
        nullptr, x, g2 + l*DD, b2n + l*DD, w1T + (size_t)l*DD*MM, bf1 + l*MM,
        nullptr, mid_bf, nullptr, MM, DD, DD, MM, 1.f);
    // x += mid @ W2 + bf2  (ksplit=8, atomic)
    k_mf64<0,1,0,0,0,0,0><<<dim3(8,8), 256, 0, stream>>>(
        mid_bf, nullptr, nullptr, nullptr, w2T + (size_t)l*MM*DD, bf2 + l*DD,
        x, nullptr, nullptr, DD, MM, MM/8, DD, 1.f);
  }

  // heads: h4 = relu(x @ [offW1|dW1|sW1|pW1] + hb4), bf16 copy of pose slice (x converted in-block)
  k_mf64<1,0,0,2,0,1,0><<<dim3(32,1), 256, 0, stream>>>(
      nullptr, x, nullptr, nullptr, headsT, hb4,
      h4, nullptr, hp_bf, 2048, DD, DD, 2048, 1.f);
  // rot6d = h_p @ pW2 + (pb2 + ibp)
  k_mf64<0,0,0,0,1,0,0><<<dim3(16,1), 256, 0, stream>>>(
      hp_bf, nullptr, nullptr, nullptr, pw2T, cvec2,
      rot6d, nullptr, nullptr, NROT, DD, DD, NROT, 1.f);
  k_final<<<BKQ, 256, 0, stream>>>(h4, rot6d, offW2, offb2, dW2, db2, sW2, sb2,
                                   K_cam, useful, t_mask, t_col, t_row, out);
}